// Round 9
// baseline (394.382 us; speedup 1.0000x reference)
//
#include <hip/hip_runtime.h>
#include <hip/hip_bf16.h>

// Problem constants (B=4, V=4096, D=256, H=4, Dh=64, KNN=10, TOPK=4, HID=64)
#define VV 4096
#define DDIM 256
#define KNN_K 10
#define TK 4

// fp32 helpers forbidding contraction (bit-faithful np mimicry — DO NOT CHANGE)
__device__ __forceinline__ float f_sq3(float x, float y, float z) {
    return __fadd_rn(__fadd_rn(__fmul_rn(x, x), __fmul_rn(y, y)), __fmul_rn(z, z));
}
__device__ __forceinline__ float f_dot3(float ax, float ay, float az,
                                        float bx, float by, float bz) {
    float d = __fmul_rn(ax, bx);
    d = __fmaf_rn(ay, by, d);
    d = __fmaf_rn(az, bz, d);
    return d;
}

// Monotone float->uint flip: u64 key (flip(d2)<<32)|idx gives EXACT lexicographic
// (d2 float-<, then lowest idx) ordering. d2 is never -0.0 (RN subtract), NaN-free.
__device__ __forceinline__ unsigned long long mkkey(float d2, int j) {
    unsigned u = __float_as_uint(d2);
    u ^= (unsigned)((int)u >> 31) | 0x80000000u;
    return ((unsigned long long)u << 32) | (unsigned)j;
}

// 4x4 fp32 outer-product accumulate, statically indexed (registers guaranteed)
__device__ __forceinline__ void fma44(const float4 a, const float4 b, float (&c)[4][4]) {
    c[0][0] = fmaf(a.x, b.x, c[0][0]); c[0][1] = fmaf(a.x, b.y, c[0][1]);
    c[0][2] = fmaf(a.x, b.z, c[0][2]); c[0][3] = fmaf(a.x, b.w, c[0][3]);
    c[1][0] = fmaf(a.y, b.x, c[1][0]); c[1][1] = fmaf(a.y, b.y, c[1][1]);
    c[1][2] = fmaf(a.y, b.z, c[1][2]); c[1][3] = fmaf(a.y, b.w, c[1][3]);
    c[2][0] = fmaf(a.z, b.x, c[2][0]); c[2][1] = fmaf(a.z, b.y, c[2][1]);
    c[2][2] = fmaf(a.z, b.z, c[2][2]); c[2][3] = fmaf(a.z, b.w, c[2][3]);
    c[3][0] = fmaf(a.w, b.x, c[3][0]); c[3][1] = fmaf(a.w, b.y, c[3][1]);
    c[3][2] = fmaf(a.w, b.z, c[3][2]); c[3][3] = fmaf(a.w, b.w, c[3][3]);
}

// ===========================================================================
// K0 (r21): merged QKV + AN GEMM, 64x64 tile, XCD-aware 2D-swizzled linear
// grid 3584. v -> xcd = v&7, s = v>>3, panel = s%14 (fast), mB = (s/14)*8+xcd.
// Each XCD processes its 32 m-groups panel-fast: all 14 B-panels (3.5 MB) and
// the A-tile stay resident in that XCD's 4MB L2 (vs ~235 MB panel-major
// re-stream). Pure index remap — numerics identical to r20 (bit-identical
// qkv/AN; same fma44 k-ascending chains). Panel 13 packs cxyzs.
// ===========================================================================
__global__ void __launch_bounds__(256) qkv_an_gemm_kernel(
    const float* __restrict__ tok,
    const float* __restrict__ Wq, const float* __restrict__ bq,
    const float* __restrict__ Wk, const float* __restrict__ bk,
    const float* __restrict__ Wv, const float* __restrict__ bv,
    const float* __restrict__ W1,
    const float* __restrict__ coords,
    float* __restrict__ qkv,
    float* __restrict__ AN,
    float4* __restrict__ cxyzs)
{
    __shared__ float As[16][68];   // [k][m]
    __shared__ float Bs[16][68];   // [k][n]

    const int v_   = blockIdx.x;              // 0..3583 linear
    const int xcd  = v_ & 7;
    const int sblk = v_ >> 3;                 // 0..447
    const int by   = sblk % 14;               // panel, fast within XCD
    const int mB   = (sblk / 14) * 8 + xcd;   // 0..255, bijective
    const int mBlock = mB * 64;
    const int tid    = threadIdx.x;
    const bool isAN  = (by >= 12);
    const int  half  = by - 12;               // 0=anchor,1=neighbor (AN only)

    // side job (panel 13): packed coords + squared norm (bit-identical f_sq3)
    if (by == 13 && tid < 64) {
        int m = mBlock + tid;
        float x = coords[m * 3 + 0], y = coords[m * 3 + 1], z = coords[m * 3 + 2];
        cxyzs[m] = make_float4(x, y, z, f_sq3(x, y, z));
    }

    const int nBlock = isAN ? 0 : by * 64;    // qkv col offset
    const int grp    = isAN ? 0 : (nBlock >> 8);
    const int nIn    = nBlock & 255;
    const float* W    = isAN ? (W1 + (size_t)half * 256 * 64)
                             : ((grp == 0) ? Wq : (grp == 1) ? Wk : Wv);
    const float* bias = (grp == 0) ? bq : (grp == 1) ? bk : bv;

    const int tx = tid & 15;     // n-dir
    const int ty = tid >> 4;     // m-dir

    const int ar  = tid >> 2;          // 0..63 (m row)
    const int ac4 = tid & 3;           // 0..3  (k float4)
    const int br  = tid >> 4;          // 0..15 (k row)
    const int bc4 = tid & 15;          // 0..15 (n float4)

    float acc[4][4] = {};

    for (int k0 = 0; k0 < 256; k0 += 16) {
        float4 a4 = *(const float4*)&tok[(size_t)(mBlock + ar) * 256 + k0 + ac4 * 4];
        As[ac4 * 4 + 0][ar] = a4.x;
        As[ac4 * 4 + 1][ar] = a4.y;
        As[ac4 * 4 + 2][ar] = a4.z;
        As[ac4 * 4 + 3][ar] = a4.w;
        float4 b4;
        if (isAN) b4 = *(const float4*)&W[(size_t)(k0 + br) * 64 + bc4 * 4];
        else      b4 = *(const float4*)&W[(size_t)(k0 + br) * 256 + nIn + bc4 * 4];
        *(float4*)&Bs[br][bc4 * 4] = b4;
        __syncthreads();
        #pragma unroll
        for (int kk = 0; kk < 16; kk++) {
            float4 av = *(const float4*)&As[kk][ty * 4];
            float4 bv4 = *(const float4*)&Bs[kk][tx * 4];
            fma44(av, bv4, acc);
        }
        __syncthreads();
    }

    if (!isAN) {
        #pragma unroll
        for (int i = 0; i < 4; i++) {
            int m = mBlock + ty * 4 + i;
            float4 o;
            o.x = acc[i][0] + bias[nIn + tx * 4 + 0];
            o.y = acc[i][1] + bias[nIn + tx * 4 + 1];
            o.z = acc[i][2] + bias[nIn + tx * 4 + 2];
            o.w = acc[i][3] + bias[nIn + tx * 4 + 3];
            *(float4*)&qkv[(size_t)m * 768 + nBlock + tx * 4] = o;
        }
    } else {
        #pragma unroll
        for (int i = 0; i < 4; i++) {
            int m = mBlock + ty * 4 + i;
            float4 o;
            o.x = acc[i][0]; o.y = acc[i][1]; o.z = acc[i][2]; o.w = acc[i][3];
            *(float4*)&AN[(size_t)m * 128 + half * 64 + tx * 4] = o;
        }
    }
}

// ===========================================================================
// K1 (r21): wave-per-query KNN + score MLP + top-4. grid 4096.
// Scan redesign: f32 (d, j) top-2 tracking — with ascending-j processing and
// strict <, EXACTLY equivalent to r16's u64 lexicographic top-2 (d2 never
// -0.0/NaN). u64 key built once per extraction round for the butterfly
// (winner lane rebuilds on consume). Butterfly + extraction order unchanged
// => selection bit-identical to r16/r20. ~25% fewer VALU insts in the scan.
// ===========================================================================
__global__ void __launch_bounds__(256) knn_score_kernel(
    const float* __restrict__ AN,
    const float4* __restrict__ cxyzs,
    const float* __restrict__ W1,
    const float* __restrict__ b1,
    const float* __restrict__ W2,
    int* __restrict__ sel)
{
    const int tid  = threadIdx.x;
    const int lane = tid & 63;
    const int wave = tid >> 6;
    const int q    = blockIdx.x * 4 + wave;   // 0..16383
    const int base = q & ~4095;
    const int v    = q & 4095;
    const float4* cx = cxyzs + base;

    __shared__ int   sKnn[4][KNN_K];
    __shared__ float sSc[4][KNN_K];
    __shared__ float sHid[4][KNN_K][65];   // pad 65: scorer stride-65 conflict-free

    float4 cq = cx[v];
    const float qx = cq.x, qy = cq.y, qz = cq.z, sqq = cq.w;

    // f32 lane-local top-2: (bd,bi) <= (sd,si) lexicographic, ascending-j scan
    float bd = 3.4e38f, sd = 3.4e38f;
    int   bi = 0x7fffffff, si = 0x7fffffff;
    unsigned long long used = 0ull;

    #pragma unroll 4
    for (int i = 0; i < 64; i++) {
        int j = i * 64 + lane;
        float4 c = cx[j];
        float dt = f_dot3(qx, qy, qz, c.x, c.y, c.z);
        float d  = __fsub_rn(__fadd_rn(sqq, c.w), __fmul_rn(2.0f, dt));
        if (d < bd)      { sd = bd; si = bi; bd = d; bi = j; }
        else if (d < sd) { sd = d;  si = j; }
    }

    unsigned long long bKey = mkkey(bd, bi);

    // ---------------- 11 extractions (round 0 = self, discarded) ------------
    #pragma unroll 1
    for (int it = 0; it < 11; it++) {
        unsigned long long rb = bKey;
        #pragma unroll
        for (int off = 1; off < 64; off <<= 1) {   // wave butterfly min (order-free)
            unsigned olo = __shfl_xor((unsigned)rb, off);
            unsigned ohi = __shfl_xor((unsigned)(rb >> 32), off);
            unsigned long long o = ((unsigned long long)ohi << 32) | olo;
            if (o < rb) rb = o;
        }
        int wj = (int)((unsigned)rb & 4095u);
        if (it >= 1 && lane == 0) sKnn[wave][it - 1] = wj;

        if (bi == wj) {                            // unique owner lane (j mod 64 = lane)
            used |= 1ull << (wj >> 6);
            bd = sd; bi = si;
            sd = 3.4e38f; si = 0x7fffffff;
            if (bi == 0x7fffffff) {                // rare: rescan unconsumed
                bd = 3.4e38f;
                #pragma unroll 1
                for (int i = 0; i < 64; i++) {
                    if ((used >> i) & 1ull) continue;
                    int j = i * 64 + lane;
                    float4 c = cx[j];
                    float dt = f_dot3(qx, qy, qz, c.x, c.y, c.z);
                    float d  = __fsub_rn(__fadd_rn(sqq, c.w), __fmul_rn(2.0f, dt));
                    if (d < bd)      { sd = bd; si = bi; bd = d; bi = j; }
                    else if (d < sd) { sd = d;  si = j; }
                }
            }
            bKey = mkkey(bd, bi);
        }
    }

    // ---------------- Phase B: gather-based score MLP (lane == h) ----------
    const float sAl = AN[(size_t)q * 128 + lane];
    const float b1l = b1[lane];
    const float wr0 = W1[(512 + 0) * 64 + lane];
    const float wr1 = W1[(512 + 1) * 64 + lane];
    const float wr2 = W1[(512 + 2) * 64 + lane];

    #pragma unroll 1
    for (int nb = 0; nb < KNN_K; nb++) {
        int kn = sKnn[wave][nb];
        float4 cn = cx[kn];
        float acc = __fadd_rn(sAl, AN[(size_t)(base + kn) * 128 + 64 + lane]);
        float rel0 = __fsub_rn(cn.x, qx);
        acc = __fmaf_rn(rel0, wr0, acc);
        float rel1 = __fsub_rn(cn.y, qy);
        acc = __fmaf_rn(rel1, wr1, acc);
        float rel2 = __fsub_rn(cn.z, qz);
        acc = __fmaf_rn(rel2, wr2, acc);
        float hid = __fadd_rn(acc, b1l);
        sHid[wave][nb][lane] = hid > 0.0f ? hid : 0.0f;
    }

    // sequential-chain scorer, EXACT r13 rounding (lanes 0..9, wave-sync)
    if (lane < KNN_K) {
        float s = 0.0f;
        #pragma unroll 8
        for (int h = 0; h < 64; h++)
            s = __fmaf_rn(sHid[wave][lane][h], W2[h], s);
        sSc[wave][lane] = s;
    }

    if (lane == 0) {          // stable top-4 -> global rows
        unsigned um = 0;
        #pragma unroll
        for (int s = 0; s < TK; s++) {
            float bests = -3.4e38f; int bj = 0;
            for (int jj = 0; jj < KNN_K; jj++) {
                if (um & (1u << jj)) continue;
                float sc = sSc[wave][jj];
                if (sc > bests) { bests = sc; bj = jj; }
            }
            um |= 1u << bj;
            sel[(size_t)q * TK + s] = base + sKnn[wave][bj];
        }
    }
}

// ===========================================================================
// K3 (r0/r13 exact, proven): per-query attention gather. grid 16384.
// ===========================================================================
__global__ void __launch_bounds__(256) attn_gather_kernel(
    const float* __restrict__ qkv, const int* __restrict__ sel,
    float* __restrict__ attnout)
{
    const int q = blockIdx.x;
    const int tid = threadIdx.x;  // = h*64 + dh

    const float qv = qkv[(size_t)q * 768 + tid];

    int rows[TK];
    #pragma unroll
    for (int s = 0; s < TK; s++) rows[s] = sel[(size_t)q * TK + s];

    float att[TK];
    #pragma unroll
    for (int s = 0; s < TK; s++) {
        float p = qv * qkv[(size_t)rows[s] * 768 + 256 + tid];
        #pragma unroll
        for (int m = 1; m < 64; m <<= 1) p += __shfl_xor(p, m);
        att[s] = p * 0.125f;   // 1/sqrt(64)
    }

    float mx  = fmaxf(fmaxf(att[0], att[1]), fmaxf(att[2], att[3]));
    float e0 = expf(att[0] - mx), e1 = expf(att[1] - mx),
          e2 = expf(att[2] - mx), e3 = expf(att[3] - mx);
    float inv = 1.0f / (e0 + e1 + e2 + e3);

    float o = (e0 * qkv[(size_t)rows[0] * 768 + 512 + tid] +
               e1 * qkv[(size_t)rows[1] * 768 + 512 + tid] +
               e2 * qkv[(size_t)rows[2] * 768 + 512 + tid] +
               e3 * qkv[(size_t)rows[3] * 768 + 512 + tid]) * inv;

    attnout[(size_t)q * 256 + tid] = o;
}

// ===========================================================================
// K4 (r0/r13 exact, proven): output projection GEMM 64x64 tile.
// out = attnout @ Wo + bo. M=16384, N=256, K=256. grid(256,4).
// ===========================================================================
__global__ void __launch_bounds__(256) wo_gemm_kernel(
    const float* __restrict__ A,
    const float* __restrict__ Wo, const float* __restrict__ bo,
    float* __restrict__ out)
{
    __shared__ float As[16][68];
    __shared__ float Bs[16][68];

    const int mBlock = blockIdx.x * 64;
    const int nBlock = blockIdx.y * 64;      // 0..192

    const int tid = threadIdx.x;
    const int tx = tid & 15;
    const int ty = tid >> 4;

    const int ar  = tid >> 2;
    const int ac4 = tid & 3;
    const int br  = tid >> 4;
    const int bc4 = tid & 15;

    float acc[4][4] = {};

    for (int k0 = 0; k0 < 256; k0 += 16) {
        float4 a4 = *(const float4*)&A[(size_t)(mBlock + ar) * 256 + k0 + ac4 * 4];
        As[ac4 * 4 + 0][ar] = a4.x;
        As[ac4 * 4 + 1][ar] = a4.y;
        As[ac4 * 4 + 2][ar] = a4.z;
        As[ac4 * 4 + 3][ar] = a4.w;
        float4 b4 = *(const float4*)&Wo[(size_t)(k0 + br) * 256 + nBlock + bc4 * 4];
        *(float4*)&Bs[br][bc4 * 4] = b4;
        __syncthreads();
        #pragma unroll
        for (int kk = 0; kk < 16; kk++) {
            float4 av = *(const float4*)&As[kk][ty * 4];
            float4 bv4 = *(const float4*)&Bs[kk][tx * 4];
            fma44(av, bv4, acc);
        }
        __syncthreads();
    }

    #pragma unroll
    for (int i = 0; i < 4; i++) {
        int m = mBlock + ty * 4 + i;
        float4 o;
        o.x = acc[i][0] + bo[nBlock + tx * 4 + 0];
        o.y = acc[i][1] + bo[nBlock + tx * 4 + 1];
        o.z = acc[i][2] + bo[nBlock + tx * 4 + 2];
        o.w = acc[i][3] + bo[nBlock + tx * 4 + 3];
        *(float4*)&out[(size_t)m * 256 + nBlock + tx * 4] = o;
    }
}

// ===========================================================================
// Fallback: round-9 fully fused kernel (PASSED @1050us), used if ws too small.
// ===========================================================================
__global__ void __launch_bounds__(256) fused_voxel_attn(
    const float* __restrict__ tok,
    const float* __restrict__ coords,
    const float* __restrict__ W1,
    const float* __restrict__ b1,
    const float* __restrict__ W2,
    const float* __restrict__ Wq, const float* __restrict__ bq,
    const float* __restrict__ Wk, const float* __restrict__ bk,
    const float* __restrict__ Wv, const float* __restrict__ bv,
    const float* __restrict__ Wo, const float* __restrict__ bo,
    float* __restrict__ out, int out_size)
{
    const int q    = blockIdx.x;
    const int b    = q >> 12;
    const int v    = q & 4095;
    const int base = q & ~4095;
    const int tid  = threadIdx.x;
    const float* cb = coords + (size_t)b * VV * 3;

    __shared__ float  sval[256];
    __shared__ int    sidx[256];
    __shared__ int    sKnn[KNN_K];
    __shared__ int    sSel[TK];
    __shared__ float  sTokA[DDIM];
    __shared__ float  sTokN[KNN_K][DDIM];
    __shared__ float  sAH[64];
    __shared__ float  sHid[KNN_K][64];
    __shared__ float  sSc[KNN_K];
    __shared__ float  sP[TK][256];
    __shared__ float  sAtt[4][TK];
    __shared__ float  sO[DDIM];

    const float qx = cb[v * 3 + 0];
    const float qy = cb[v * 3 + 1];
    const float qz = cb[v * 3 + 2];
    const float sqq = f_sq3(qx, qy, qz);

    float d2[16];
    #pragma unroll
    for (int i = 0; i < 16; i++) {
        int j = tid + i * 256;
        float xj = cb[j * 3 + 0], yj = cb[j * 3 + 1], zj = cb[j * 3 + 2];
        float sqj = f_sq3(xj, yj, zj);
        float dt  = f_dot3(qx, qy, qz, xj, yj, zj);
        d2[i] = __fsub_rn(__fadd_rn(sqq, sqj), __fmul_rn(2.0f, dt));
    }

    unsigned used = 0;
    for (int it = 0; it < 11; it++) {
        float best = 3.4e38f;
        int bi = 0x7fffffff;
        #pragma unroll
        for (int i = 0; i < 16; i++) {
            if (used & (1u << i)) continue;
            if (d2[i] < best) { best = d2[i]; bi = tid + i * 256; }
        }
        sval[tid] = best;
        sidx[tid] = bi;
        __syncthreads();
        for (int s = 128; s > 0; s >>= 1) {
            if (tid < s) {
                float v2 = sval[tid + s];
                int   i2 = sidx[tid + s];
                if (v2 < sval[tid] || (v2 == sval[tid] && i2 < sidx[tid])) {
                    sval[tid] = v2; sidx[tid] = i2;
                }
            }
            __syncthreads();
        }
        int w = sidx[0] & 4095;
        __syncthreads();
        if (it >= 1 && tid == 0) sKnn[it - 1] = w;
        if ((w & 255) == tid) used |= 1u << (w >> 8);
    }
    __syncthreads();

    sTokA[tid] = tok[(size_t)q * DDIM + tid];
    for (int nb = 0; nb < KNN_K; nb++)
        sTokN[nb][tid] = tok[(size_t)(base + sKnn[nb]) * DDIM + tid];
    __syncthreads();

    if (tid < 64) {
        float a = 0.0f;
        for (int k = 0; k < 256; k++)
            a = __fmaf_rn(sTokA[k], W1[k * 64 + tid], a);
        sAH[tid] = a;
    }
    __syncthreads();

    for (int idx = tid; idx < KNN_K * 64; idx += 256) {
        int nb = idx >> 6;
        int h  = idx & 63;
        float acc = sAH[h];
        const float* tn = sTokN[nb];
        for (int k = 0; k < 256; k++)
            acc = __fmaf_rn(tn[k], W1[(256 + k) * 64 + h], acc);
        #pragma unroll
        for (int c = 0; c < 3; c++) {
            float rel = __fsub_rn(cb[sKnn[nb] * 3 + c], cb[v * 3 + c]);
            acc = __fmaf_rn(rel, W1[(512 + c) * 64 + h], acc);
        }
        float hid = __fadd_rn(acc, b1[h]);
        sHid[nb][h] = hid > 0.0f ? hid : 0.0f;
    }
    __syncthreads();

    if (tid < KNN_K) {
        float s = 0.0f;
        for (int h = 0; h < 64; h++)
            s = __fmaf_rn(sHid[tid][h], W2[h], s);
        sSc[tid] = s;
    }
    __syncthreads();

    if (tid == 0) {
        unsigned um = 0;
        #pragma unroll
        for (int s = 0; s < TK; s++) {
            float best = -3.4e38f; int bj = 0;
            for (int jj = 0; jj < KNN_K; jj++) {
                if (um & (1u << jj)) continue;
                if (sSc[jj] > best) { best = sSc[jj]; bj = jj; }
            }
            um |= 1u << bj;
            sSel[s] = bj;
        }
    }
    __syncthreads();

    int ss[TK];
    float k_acc[TK], v_acc[TK];
    #pragma unroll
    for (int s = 0; s < TK; s++) {
        ss[s] = sSel[s];
        k_acc[s] = bk[tid];
        v_acc[s] = bv[tid];
    }
    float q_acc = bq[tid];

    for (int k = 0; k < 256; k++) {
        float wq = Wq[k * 256 + tid];
        float wk = Wk[k * 256 + tid];
        float wv = Wv[k * 256 + tid];
        q_acc += sTokA[k] * wq;
        #pragma unroll
        for (int s = 0; s < TK; s++) {
            float x = sTokN[ss[s]][k];
            k_acc[s] += x * wk;
            v_acc[s] += x * wv;
        }
    }

    #pragma unroll
    for (int s = 0; s < TK; s++) sP[s][tid] = q_acc * k_acc[s];
    __syncthreads();

    if (tid < 16) {
        int h = tid >> 2, s = tid & 3;
        float p = 0.0f;
        for (int d = 0; d < 64; d++) p += sP[s][h * 64 + d];
        sAtt[h][s] = p * 0.125f;
    }
    __syncthreads();

    const int hh = tid >> 6;
    float a0 = sAtt[hh][0], a1 = sAtt[hh][1], a2 = sAtt[hh][2], a3 = sAtt[hh][3];
    float mx  = fmaxf(fmaxf(a0, a1), fmaxf(a2, a3));
    float e0 = expf(a0 - mx), e1 = expf(a1 - mx), e2 = expf(a2 - mx), e3 = expf(a3 - mx);
    float inv = 1.0f / (e0 + e1 + e2 + e3);
    float o = (e0 * v_acc[0] + e1 * v_acc[1] + e2 * v_acc[2] + e3 * v_acc[3]) * inv;

    sO[tid] = o;
    __syncthreads();

    float a = bo[tid];
    for (int e = 0; e < 256; e++) a += sO[e] * Wo[e * 256 + tid];
    int oidx = q * DDIM + tid;
    if (oidx < out_size)
        out[oidx] = a;
}

// ---------------------------------------------------------------------------
// Launcher. ABI-bilingual size-walk (validated r8-r11). r21 ws layout:
//   sel     @ 0          : 16384*4*4   =    262,144
//   AN      @ 262,144    : 16384*128*4 =  8,388,608  (ends  8,650,752)
//   attnout @ 262,144    : 16384*256*4 = 16,777,216  (ends 17,039,360) ALIAS of AN
//   qkv     @ 17,039,360 : 16384*768*4 = 50,331,648  (ends 67,371,008)
//   cxyzs   @ 67,371,008 : 16384*16    =    262,144  (ends 67,633,152)
// NEED = 67,633,152 < 75,497,472 (r11-confirmed available).
// Hazards: AN,cxyzs,qkv written(K0) -> AN,cxyzs read(K1), qkv read(K3);
// attnout written(K3) after AN dead; wo(K4) reads attnout. Stream order safe.
// ---------------------------------------------------------------------------
extern "C" void kernel_launch(void* const* d_in, const int* in_sizes, int n_in,
                              void* d_out, int out_size, void* d_ws, size_t ws_size,
                              hipStream_t stream)
{
    const long long want[13] = {4194304LL, 49152LL, 32960LL, 64LL, 64LL,
                                65536LL, 256LL, 65536LL, 256LL,
                                65536LL, 256LL, 65536LL, 256LL};
    int idx[13];
    const int n = n_in;

    const long long* s64 = (const long long*)(const void*)in_sizes;
    const int*       s32 = in_sizes;

    bool ok = false;

    if (n >= 13 && s64[0] == want[0]) {   // int64 interpretation (gated)
        ok = true;
        int walk = 0;
        for (int t = 0; t < 13; t++) {
            int f = -1;
            for (int i = walk; i < n; i++) {
                if (s64[i] == want[t]) { f = i; break; }
            }
            if (f < 0) { ok = false; break; }
            idx[t] = f; walk = f + 1;
        }
    }

    if (!ok) {                            // int32 interpretation
        ok = true;
        int walk = 0;
        for (int t = 0; t < 13; t++) {
            int f = -1;
            for (int i = walk; i < n; i++) {
                if ((long long)s32[i] == want[t]) { f = i; break; }
            }
            if (f < 0) { ok = false; break; }
            idx[t] = f; walk = f + 1;
        }
    }

    if (!ok) return;   // unexpected layout: clean failure, no crash

    const float* tok    = (const float*)d_in[idx[0]];
    const float* coords = (const float*)d_in[idx[1]];
    const float* W1     = (const float*)d_in[idx[2]];
    const float* b1     = (const float*)d_in[idx[3]];
    const float* W2     = (const float*)d_in[idx[4]];
    const float* Wq     = (const float*)d_in[idx[5]];
    const float* bq     = (const float*)d_in[idx[6]];
    const float* Wk     = (const float*)d_in[idx[7]];
    const float* bk     = (const float*)d_in[idx[8]];
    const float* Wv     = (const float*)d_in[idx[9]];
    const float* bv     = (const float*)d_in[idx[10]];
    const float* Wo     = (const float*)d_in[idx[11]];
    const float* bo     = (const float*)d_in[idx[12]];
    float* out = (float*)d_out;

    const size_t NEED = 67633152;
    if (ws_size >= NEED) {
        char* ws = (char*)d_ws;
        int*    sel     = (int*)   (ws + 0);
        float*  AN      = (float*) (ws + 262144);
        float*  attnout = (float*) (ws + 262144);    // aliases AN (dead after K1)
        float*  qkv     = (float*) (ws + 17039360);
        float4* cxyzs   = (float4*)(ws + 67371008);

        qkv_an_gemm_kernel<<<dim3(3584), dim3(256), 0, stream>>>(
            tok, Wq, bq, Wk, bk, Wv, bv, W1, coords, qkv, AN, cxyzs);
        knn_score_kernel<<<dim3(4096), dim3(256), 0, stream>>>(AN, cxyzs, W1, b1, W2, sel);
        attn_gather_kernel<<<dim3(16384), dim3(256), 0, stream>>>(qkv, sel, attnout);
        wo_gemm_kernel<<<dim3(256, 4), dim3(256), 0, stream>>>(attnout, Wo, bo, out);
    } else {
        fused_voxel_attn<<<dim3(16384), dim3(256), 0, stream>>>(
            tok, coords, W1, b1, W2, Wq, bq, Wk, bk, Wv, bv, Wo, bo, out, out_size);
    }
}

// Round 10
// 381.056 us; speedup vs baseline: 1.0350x; 1.0350x over previous
//
#include <hip/hip_runtime.h>
#include <hip/hip_bf16.h>

// Problem constants (B=4, V=4096, D=256, H=4, Dh=64, KNN=10, TOPK=4, HID=64)
#define VV 4096
#define DDIM 256
#define KNN_K 10
#define TK 4

// fp32 helpers forbidding contraction (bit-faithful np mimicry — DO NOT CHANGE)
__device__ __forceinline__ float f_sq3(float x, float y, float z) {
    return __fadd_rn(__fadd_rn(__fmul_rn(x, x), __fmul_rn(y, y)), __fmul_rn(z, z));
}
__device__ __forceinline__ float f_dot3(float ax, float ay, float az,
                                        float bx, float by, float bz) {
    float d = __fmul_rn(ax, bx);
    d = __fmaf_rn(ay, by, d);
    d = __fmaf_rn(az, bz, d);
    return d;
}

// Monotone float->uint flip: u64 key (flip(d2)<<32)|idx gives EXACT lexicographic
// (d2 float-<, then lowest idx) ordering. d2 is never -0.0 (RN subtract), NaN-free.
__device__ __forceinline__ unsigned long long mkkey(float d2, int j) {
    unsigned u = __float_as_uint(d2);
    u ^= (unsigned)((int)u >> 31) | 0x80000000u;
    return ((unsigned long long)u << 32) | (unsigned)j;
}

// 4x4 fp32 outer-product accumulate, statically indexed (registers guaranteed)
__device__ __forceinline__ void fma44(const float4 a, const float4 b, float (&c)[4][4]) {
    c[0][0] = fmaf(a.x, b.x, c[0][0]); c[0][1] = fmaf(a.x, b.y, c[0][1]);
    c[0][2] = fmaf(a.x, b.z, c[0][2]); c[0][3] = fmaf(a.x, b.w, c[0][3]);
    c[1][0] = fmaf(a.y, b.x, c[1][0]); c[1][1] = fmaf(a.y, b.y, c[1][1]);
    c[1][2] = fmaf(a.y, b.z, c[1][2]); c[1][3] = fmaf(a.y, b.w, c[1][3]);
    c[2][0] = fmaf(a.z, b.x, c[2][0]); c[2][1] = fmaf(a.z, b.y, c[2][1]);
    c[2][2] = fmaf(a.z, b.z, c[2][2]); c[2][3] = fmaf(a.z, b.w, c[2][3]);
    c[3][0] = fmaf(a.w, b.x, c[3][0]); c[3][1] = fmaf(a.w, b.y, c[3][1]);
    c[3][2] = fmaf(a.w, b.z, c[3][2]); c[3][3] = fmaf(a.w, b.w, c[3][3]);
}

// ===========================================================================
// K0 (r20-exact, best measured): merged QKV + AN GEMM at 64x64 tile.
// grid(256,14), block 256. Panels 0..11 = Q|K|V. Panels 12..13 = AN halves
// (W1[0:256]/W1[256:512], ldb=64, no bias, fma44 k-ascending chain => AN
// bit-identical). Panel 13 packs cxyzs. (r21's XCD swizzle reverted: within
// noise, and minimizing variables while knn is the experiment this round.)
// ===========================================================================
__global__ void __launch_bounds__(256) qkv_an_gemm_kernel(
    const float* __restrict__ tok,
    const float* __restrict__ Wq, const float* __restrict__ bq,
    const float* __restrict__ Wk, const float* __restrict__ bk,
    const float* __restrict__ Wv, const float* __restrict__ bv,
    const float* __restrict__ W1,
    const float* __restrict__ coords,
    float* __restrict__ qkv,
    float* __restrict__ AN,
    float4* __restrict__ cxyzs)
{
    __shared__ float As[16][68];   // [k][m]
    __shared__ float Bs[16][68];   // [k][n]

    const int mBlock = blockIdx.x * 64;
    const int by     = blockIdx.y;            // 0..11 qkv, 12..13 AN
    const int tid    = threadIdx.x;
    const bool isAN  = (by >= 12);
    const int  half  = by - 12;               // 0=anchor,1=neighbor (AN only)

    // side job (panel 13): packed coords + squared norm (bit-identical f_sq3)
    if (by == 13 && tid < 64) {
        int m = mBlock + tid;
        float x = coords[m * 3 + 0], y = coords[m * 3 + 1], z = coords[m * 3 + 2];
        cxyzs[m] = make_float4(x, y, z, f_sq3(x, y, z));
    }

    const int nBlock = isAN ? 0 : by * 64;    // qkv col offset
    const int grp    = isAN ? 0 : (nBlock >> 8);
    const int nIn    = nBlock & 255;
    const float* W    = isAN ? (W1 + (size_t)half * 256 * 64)
                             : ((grp == 0) ? Wq : (grp == 1) ? Wk : Wv);
    const float* bias = (grp == 0) ? bq : (grp == 1) ? bk : bv;

    const int tx = tid & 15;     // n-dir
    const int ty = tid >> 4;     // m-dir

    const int ar  = tid >> 2;          // 0..63 (m row)
    const int ac4 = tid & 3;           // 0..3  (k float4)
    const int br  = tid >> 4;          // 0..15 (k row)
    const int bc4 = tid & 15;          // 0..15 (n float4)

    float acc[4][4] = {};

    for (int k0 = 0; k0 < 256; k0 += 16) {
        float4 a4 = *(const float4*)&tok[(size_t)(mBlock + ar) * 256 + k0 + ac4 * 4];
        As[ac4 * 4 + 0][ar] = a4.x;
        As[ac4 * 4 + 1][ar] = a4.y;
        As[ac4 * 4 + 2][ar] = a4.z;
        As[ac4 * 4 + 3][ar] = a4.w;
        float4 b4;
        if (isAN) b4 = *(const float4*)&W[(size_t)(k0 + br) * 64 + bc4 * 4];
        else      b4 = *(const float4*)&W[(size_t)(k0 + br) * 256 + nIn + bc4 * 4];
        *(float4*)&Bs[br][bc4 * 4] = b4;
        __syncthreads();
        #pragma unroll
        for (int kk = 0; kk < 16; kk++) {
            float4 av = *(const float4*)&As[kk][ty * 4];
            float4 bv4 = *(const float4*)&Bs[kk][tx * 4];
            fma44(av, bv4, acc);
        }
        __syncthreads();
    }

    if (!isAN) {
        #pragma unroll
        for (int i = 0; i < 4; i++) {
            int m = mBlock + ty * 4 + i;
            float4 o;
            o.x = acc[i][0] + bias[nIn + tx * 4 + 0];
            o.y = acc[i][1] + bias[nIn + tx * 4 + 1];
            o.z = acc[i][2] + bias[nIn + tx * 4 + 2];
            o.w = acc[i][3] + bias[nIn + tx * 4 + 3];
            *(float4*)&qkv[(size_t)m * 768 + nBlock + tx * 4] = o;
        }
    } else {
        #pragma unroll
        for (int i = 0; i < 4; i++) {
            int m = mBlock + ty * 4 + i;
            float4 o;
            o.x = acc[i][0]; o.y = acc[i][1]; o.z = acc[i][2]; o.w = acc[i][3];
            *(float4*)&AN[(size_t)m * 128 + half * 64 + tx * 4] = o;
        }
    }
}

// ===========================================================================
// K1 (r22): TWO queries per wave, r16's u64 machinery duplicated. grid 2048.
// Each cx[j] load feeds two INDEPENDENT (best,second) chains; extraction
// rounds run two independent u64 butterflies (ILP fills latency slots; no new
// dependence — each chain is bit-for-bit the r16 chain). Loads per query
// halve. Selection bit-identical to r16/r20. Scorer lanes 0-9 (qA) || 32-41
// (qB). [r17/r21 lesson: never replace the u64 ops; only duplicate them.]
// ===========================================================================
__global__ void __launch_bounds__(256) knn_score_kernel(
    const float* __restrict__ AN,
    const float4* __restrict__ cxyzs,
    const float* __restrict__ W1,
    const float* __restrict__ b1,
    const float* __restrict__ W2,
    int* __restrict__ sel)
{
    const int tid  = threadIdx.x;
    const int lane = tid & 63;
    const int wave = tid >> 6;
    const int qA   = blockIdx.x * 8 + wave * 2;   // even, 0..16382
    const int qB   = qA + 1;
    const int base = qA & ~4095;                  // qB same batch (8-aligned)
    const float4* cx = cxyzs + base;

    __shared__ int   sKnn[4][2][KNN_K];
    __shared__ float sSc[4][2][KNN_K];
    __shared__ float sHid[4][2][KNN_K][65];   // stride-65: scorer conflict-free

    float4 cqA = cx[qA & 4095];
    float4 cqB = cx[qB & 4095];

    unsigned long long bestA = ~0ull, secondA = ~0ull, usedA = 0ull;
    unsigned long long bestB = ~0ull, secondB = ~0ull, usedB = 0ull;

    #pragma unroll 4
    for (int i = 0; i < 64; i++) {
        int j = i * 64 + lane;
        float4 c = cx[j];
        float dtA = f_dot3(cqA.x, cqA.y, cqA.z, c.x, c.y, c.z);
        float dA  = __fsub_rn(__fadd_rn(cqA.w, c.w), __fmul_rn(2.0f, dtA));
        unsigned long long kA = mkkey(dA, j);
        if (kA < bestA) { secondA = bestA; bestA = kA; }
        else if (kA < secondA) { secondA = kA; }
        float dtB = f_dot3(cqB.x, cqB.y, cqB.z, c.x, c.y, c.z);
        float dB  = __fsub_rn(__fadd_rn(cqB.w, c.w), __fmul_rn(2.0f, dtB));
        unsigned long long kB = mkkey(dB, j);
        if (kB < bestB) { secondB = bestB; bestB = kB; }
        else if (kB < secondB) { secondB = kB; }
    }

    // ------------- 11 extractions x 2 queries (round 0 = self) -------------
    #pragma unroll 1
    for (int it = 0; it < 11; it++) {
        unsigned long long rbA = bestA, rbB = bestB;
        #pragma unroll
        for (int off = 1; off < 64; off <<= 1) {   // two independent butterflies
            unsigned aLo = __shfl_xor((unsigned)rbA, off);
            unsigned aHi = __shfl_xor((unsigned)(rbA >> 32), off);
            unsigned bLo = __shfl_xor((unsigned)rbB, off);
            unsigned bHi = __shfl_xor((unsigned)(rbB >> 32), off);
            unsigned long long oA = ((unsigned long long)aHi << 32) | aLo;
            unsigned long long oB = ((unsigned long long)bHi << 32) | bLo;
            if (oA < rbA) rbA = oA;
            if (oB < rbB) rbB = oB;
        }
        int wjA = (int)((unsigned)rbA & 4095u);
        int wjB = (int)((unsigned)rbB & 4095u);
        if (it >= 1 && lane == 0) {
            sKnn[wave][0][it - 1] = wjA;
            sKnn[wave][1][it - 1] = wjB;
        }

        if ((unsigned)bestA == (unsigned)rbA) {    // lane owned qA's winner
            usedA |= 1ull << (wjA >> 6);
            bestA = secondA; secondA = ~0ull;
            if (bestA == ~0ull) {                  // rare rescan (qA)
                #pragma unroll 1
                for (int i = 0; i < 64; i++) {
                    if ((usedA >> i) & 1ull) continue;
                    int j = i * 64 + lane;
                    float4 c = cx[j];
                    float dt = f_dot3(cqA.x, cqA.y, cqA.z, c.x, c.y, c.z);
                    float d  = __fsub_rn(__fadd_rn(cqA.w, c.w), __fmul_rn(2.0f, dt));
                    unsigned long long k = mkkey(d, j);
                    if (k < bestA) { secondA = bestA; bestA = k; }
                    else if (k < secondA) { secondA = k; }
                }
            }
        }
        if ((unsigned)bestB == (unsigned)rbB) {    // lane owned qB's winner
            usedB |= 1ull << (wjB >> 6);
            bestB = secondB; secondB = ~0ull;
            if (bestB == ~0ull) {                  // rare rescan (qB)
                #pragma unroll 1
                for (int i = 0; i < 64; i++) {
                    if ((usedB >> i) & 1ull) continue;
                    int j = i * 64 + lane;
                    float4 c = cx[j];
                    float dt = f_dot3(cqB.x, cqB.y, cqB.z, c.x, c.y, c.z);
                    float d  = __fsub_rn(__fadd_rn(cqB.w, c.w), __fmul_rn(2.0f, dt));
                    unsigned long long k = mkkey(d, j);
                    if (k < bestB) { secondB = bestB; bestB = k; }
                    else if (k < secondB) { secondB = k; }
                }
            }
        }
    }

    // ------------- Phase B: gather-based score MLP (lane == h), 2 queries ---
    const float sAlA = AN[(size_t)qA * 128 + lane];
    const float sAlB = AN[(size_t)qB * 128 + lane];
    const float b1l = b1[lane];
    const float wr0 = W1[(512 + 0) * 64 + lane];
    const float wr1 = W1[(512 + 1) * 64 + lane];
    const float wr2 = W1[(512 + 2) * 64 + lane];

    #pragma unroll 1
    for (int nb = 0; nb < KNN_K; nb++) {
        int knA = sKnn[wave][0][nb];
        int knB = sKnn[wave][1][nb];
        float4 cnA = cx[knA];
        float4 cnB = cx[knB];
        float accA = __fadd_rn(sAlA, AN[(size_t)(base + knA) * 128 + 64 + lane]);
        float accB = __fadd_rn(sAlB, AN[(size_t)(base + knB) * 128 + 64 + lane]);
        accA = __fmaf_rn(__fsub_rn(cnA.x, cqA.x), wr0, accA);
        accB = __fmaf_rn(__fsub_rn(cnB.x, cqB.x), wr0, accB);
        accA = __fmaf_rn(__fsub_rn(cnA.y, cqA.y), wr1, accA);
        accB = __fmaf_rn(__fsub_rn(cnB.y, cqB.y), wr1, accB);
        accA = __fmaf_rn(__fsub_rn(cnA.z, cqA.z), wr2, accA);
        accB = __fmaf_rn(__fsub_rn(cnB.z, cqB.z), wr2, accB);
        float hidA = __fadd_rn(accA, b1l);
        float hidB = __fadd_rn(accB, b1l);
        sHid[wave][0][nb][lane] = hidA > 0.0f ? hidA : 0.0f;
        sHid[wave][1][nb][lane] = hidB > 0.0f ? hidB : 0.0f;
    }

    // sequential-chain scorer, EXACT r13 rounding: lanes 0-9 (qA) || 32-41 (qB)
    {
        int sqi = -1, row = 0;
        if (lane < KNN_K)                         { sqi = 0; row = lane; }
        else if (lane >= 32 && lane < 32 + KNN_K) { sqi = 1; row = lane - 32; }
        if (sqi >= 0) {
            float s = 0.0f;
            #pragma unroll 8
            for (int h = 0; h < 64; h++)
                s = __fmaf_rn(sHid[wave][sqi][row][h], W2[h], s);
            sSc[wave][sqi][row] = s;
        }
    }

    if (lane == 0 || lane == 32) {            // stable top-4, one lane per query
        const int sqi = lane >> 5;
        const int qq  = sqi == 0 ? qA : qB;
        unsigned um = 0;
        #pragma unroll
        for (int s = 0; s < TK; s++) {
            float bests = -3.4e38f; int bj = 0;
            for (int jj = 0; jj < KNN_K; jj++) {
                if (um & (1u << jj)) continue;
                float sc = sSc[wave][sqi][jj];
                if (sc > bests) { bests = sc; bj = jj; }
            }
            um |= 1u << bj;
            sel[(size_t)qq * TK + s] = base + sKnn[wave][sqi][bj];
        }
    }
}

// ===========================================================================
// K3 (r0/r13 exact, proven): per-query attention gather. grid 16384.
// ===========================================================================
__global__ void __launch_bounds__(256) attn_gather_kernel(
    const float* __restrict__ qkv, const int* __restrict__ sel,
    float* __restrict__ attnout)
{
    const int q = blockIdx.x;
    const int tid = threadIdx.x;  // = h*64 + dh

    const float qv = qkv[(size_t)q * 768 + tid];

    int rows[TK];
    #pragma unroll
    for (int s = 0; s < TK; s++) rows[s] = sel[(size_t)q * TK + s];

    float att[TK];
    #pragma unroll
    for (int s = 0; s < TK; s++) {
        float p = qv * qkv[(size_t)rows[s] * 768 + 256 + tid];
        #pragma unroll
        for (int m = 1; m < 64; m <<= 1) p += __shfl_xor(p, m);
        att[s] = p * 0.125f;   // 1/sqrt(64)
    }

    float mx  = fmaxf(fmaxf(att[0], att[1]), fmaxf(att[2], att[3]));
    float e0 = expf(att[0] - mx), e1 = expf(att[1] - mx),
          e2 = expf(att[2] - mx), e3 = expf(att[3] - mx);
    float inv = 1.0f / (e0 + e1 + e2 + e3);

    float o = (e0 * qkv[(size_t)rows[0] * 768 + 512 + tid] +
               e1 * qkv[(size_t)rows[1] * 768 + 512 + tid] +
               e2 * qkv[(size_t)rows[2] * 768 + 512 + tid] +
               e3 * qkv[(size_t)rows[3] * 768 + 512 + tid]) * inv;

    attnout[(size_t)q * 256 + tid] = o;
}

// ===========================================================================
// K4 (r0/r13 exact, proven): output projection GEMM 64x64 tile.
// out = attnout @ Wo + bo. M=16384, N=256, K=256. grid(256,4).
// ===========================================================================
__global__ void __launch_bounds__(256) wo_gemm_kernel(
    const float* __restrict__ A,
    const float* __restrict__ Wo, const float* __restrict__ bo,
    float* __restrict__ out)
{
    __shared__ float As[16][68];
    __shared__ float Bs[16][68];

    const int mBlock = blockIdx.x * 64;
    const int nBlock = blockIdx.y * 64;      // 0..192

    const int tid = threadIdx.x;
    const int tx = tid & 15;
    const int ty = tid >> 4;

    const int ar  = tid >> 2;
    const int ac4 = tid & 3;
    const int br  = tid >> 4;
    const int bc4 = tid & 15;

    float acc[4][4] = {};

    for (int k0 = 0; k0 < 256; k0 += 16) {
        float4 a4 = *(const float4*)&A[(size_t)(mBlock + ar) * 256 + k0 + ac4 * 4];
        As[ac4 * 4 + 0][ar] = a4.x;
        As[ac4 * 4 + 1][ar] = a4.y;
        As[ac4 * 4 + 2][ar] = a4.z;
        As[ac4 * 4 + 3][ar] = a4.w;
        float4 b4 = *(const float4*)&Wo[(size_t)(k0 + br) * 256 + nBlock + bc4 * 4];
        *(float4*)&Bs[br][bc4 * 4] = b4;
        __syncthreads();
        #pragma unroll
        for (int kk = 0; kk < 16; kk++) {
            float4 av = *(const float4*)&As[kk][ty * 4];
            float4 bv4 = *(const float4*)&Bs[kk][tx * 4];
            fma44(av, bv4, acc);
        }
        __syncthreads();
    }

    #pragma unroll
    for (int i = 0; i < 4; i++) {
        int m = mBlock + ty * 4 + i;
        float4 o;
        o.x = acc[i][0] + bo[nBlock + tx * 4 + 0];
        o.y = acc[i][1] + bo[nBlock + tx * 4 + 1];
        o.z = acc[i][2] + bo[nBlock + tx * 4 + 2];
        o.w = acc[i][3] + bo[nBlock + tx * 4 + 3];
        *(float4*)&out[(size_t)m * 256 + nBlock + tx * 4] = o;
    }
}

// ===========================================================================
// Fallback: round-9 fully fused kernel (PASSED @1050us), used if ws too small.
// ===========================================================================
__global__ void __launch_bounds__(256) fused_voxel_attn(
    const float* __restrict__ tok,
    const float* __restrict__ coords,
    const float* __restrict__ W1,
    const float* __restrict__ b1,
    const float* __restrict__ W2,
    const float* __restrict__ Wq, const float* __restrict__ bq,
    const float* __restrict__ Wk, const float* __restrict__ bk,
    const float* __restrict__ Wv, const float* __restrict__ bv,
    const float* __restrict__ Wo, const float* __restrict__ bo,
    float* __restrict__ out, int out_size)
{
    const int q    = blockIdx.x;
    const int b    = q >> 12;
    const int v    = q & 4095;
    const int base = q & ~4095;
    const int tid  = threadIdx.x;
    const float* cb = coords + (size_t)b * VV * 3;

    __shared__ float  sval[256];
    __shared__ int    sidx[256];
    __shared__ int    sKnn[KNN_K];
    __shared__ int    sSel[TK];
    __shared__ float  sTokA[DDIM];
    __shared__ float  sTokN[KNN_K][DDIM];
    __shared__ float  sAH[64];
    __shared__ float  sHid[KNN_K][64];
    __shared__ float  sSc[KNN_K];
    __shared__ float  sP[TK][256];
    __shared__ float  sAtt[4][TK];
    __shared__ float  sO[DDIM];

    const float qx = cb[v * 3 + 0];
    const float qy = cb[v * 3 + 1];
    const float qz = cb[v * 3 + 2];
    const float sqq = f_sq3(qx, qy, qz);

    float d2[16];
    #pragma unroll
    for (int i = 0; i < 16; i++) {
        int j = tid + i * 256;
        float xj = cb[j * 3 + 0], yj = cb[j * 3 + 1], zj = cb[j * 3 + 2];
        float sqj = f_sq3(xj, yj, zj);
        float dt  = f_dot3(qx, qy, qz, xj, yj, zj);
        d2[i] = __fsub_rn(__fadd_rn(sqq, sqj), __fmul_rn(2.0f, dt));
    }

    unsigned used = 0;
    for (int it = 0; it < 11; it++) {
        float best = 3.4e38f;
        int bi = 0x7fffffff;
        #pragma unroll
        for (int i = 0; i < 16; i++) {
            if (used & (1u << i)) continue;
            if (d2[i] < best) { best = d2[i]; bi = tid + i * 256; }
        }
        sval[tid] = best;
        sidx[tid] = bi;
        __syncthreads();
        for (int s = 128; s > 0; s >>= 1) {
            if (tid < s) {
                float v2 = sval[tid + s];
                int   i2 = sidx[tid + s];
                if (v2 < sval[tid] || (v2 == sval[tid] && i2 < sidx[tid])) {
                    sval[tid] = v2; sidx[tid] = i2;
                }
            }
            __syncthreads();
        }
        int w = sidx[0] & 4095;
        __syncthreads();
        if (it >= 1 && tid == 0) sKnn[it - 1] = w;
        if ((w & 255) == tid) used |= 1u << (w >> 8);
    }
    __syncthreads();

    sTokA[tid] = tok[(size_t)q * DDIM + tid];
    for (int nb = 0; nb < KNN_K; nb++)
        sTokN[nb][tid] = tok[(size_t)(base + sKnn[nb]) * DDIM + tid];
    __syncthreads();

    if (tid < 64) {
        float a = 0.0f;
        for (int k = 0; k < 256; k++)
            a = __fmaf_rn(sTokA[k], W1[k * 64 + tid], a);
        sAH[tid] = a;
    }
    __syncthreads();

    for (int idx = tid; idx < KNN_K * 64; idx += 256) {
        int nb = idx >> 6;
        int h  = idx & 63;
        float acc = sAH[h];
        const float* tn = sTokN[nb];
        for (int k = 0; k < 256; k++)
            acc = __fmaf_rn(tn[k], W1[(256 + k) * 64 + h], acc);
        #pragma unroll
        for (int c = 0; c < 3; c++) {
            float rel = __fsub_rn(cb[sKnn[nb] * 3 + c], cb[v * 3 + c]);
            acc = __fmaf_rn(rel, W1[(512 + c) * 64 + h], acc);
        }
        float hid = __fadd_rn(acc, b1[h]);
        sHid[nb][h] = hid > 0.0f ? hid : 0.0f;
    }
    __syncthreads();

    if (tid < KNN_K) {
        float s = 0.0f;
        for (int h = 0; h < 64; h++)
            s = __fmaf_rn(sHid[tid][h], W2[h], s);
        sSc[tid] = s;
    }
    __syncthreads();

    if (tid == 0) {
        unsigned um = 0;
        #pragma unroll
        for (int s = 0; s < TK; s++) {
            float best = -3.4e38f; int bj = 0;
            for (int jj = 0; jj < KNN_K; jj++) {
                if (um & (1u << jj)) continue;
                if (sSc[jj] > best) { best = sSc[jj]; bj = jj; }
            }
            um |= 1u << bj;
            sSel[s] = bj;
        }
    }
    __syncthreads();

    int ss[TK];
    float k_acc[TK], v_acc[TK];
    #pragma unroll
    for (int s = 0; s < TK; s++) {
        ss[s] = sSel[s];
        k_acc[s] = bk[tid];
        v_acc[s] = bv[tid];
    }
    float q_acc = bq[tid];

    for (int k = 0; k < 256; k++) {
        float wq = Wq[k * 256 + tid];
        float wk = Wk[k * 256 + tid];
        float wv = Wv[k * 256 + tid];
        q_acc += sTokA[k] * wq;
        #pragma unroll
        for (int s = 0; s < TK; s++) {
            float x = sTokN[ss[s]][k];
            k_acc[s] += x * wk;
            v_acc[s] += x * wv;
        }
    }

    #pragma unroll
    for (int s = 0; s < TK; s++) sP[s][tid] = q_acc * k_acc[s];
    __syncthreads();

    if (tid < 16) {
        int h = tid >> 2, s = tid & 3;
        float p = 0.0f;
        for (int d = 0; d < 64; d++) p += sP[s][h * 64 + d];
        sAtt[h][s] = p * 0.125f;
    }
    __syncthreads();

    const int hh = tid >> 6;
    float a0 = sAtt[hh][0], a1 = sAtt[hh][1], a2 = sAtt[hh][2], a3 = sAtt[hh][3];
    float mx  = fmaxf(fmaxf(a0, a1), fmaxf(a2, a3));
    float e0 = expf(a0 - mx), e1 = expf(a1 - mx), e2 = expf(a2 - mx), e3 = expf(a3 - mx);
    float inv = 1.0f / (e0 + e1 + e2 + e3);
    float o = (e0 * v_acc[0] + e1 * v_acc[1] + e2 * v_acc[2] + e3 * v_acc[3]) * inv;

    sO[tid] = o;
    __syncthreads();

    float a = bo[tid];
    for (int e = 0; e < 256; e++) a += sO[e] * Wo[e * 256 + tid];
    int oidx = q * DDIM + tid;
    if (oidx < out_size)
        out[oidx] = a;
}

// ---------------------------------------------------------------------------
// Launcher. ABI-bilingual size-walk (validated r8-r11). r22 ws layout:
//   sel     @ 0          : 16384*4*4   =    262,144
//   AN      @ 262,144    : 16384*128*4 =  8,388,608  (ends  8,650,752)
//   attnout @ 262,144    : 16384*256*4 = 16,777,216  (ends 17,039,360) ALIAS of AN
//   qkv     @ 17,039,360 : 16384*768*4 = 50,331,648  (ends 67,371,008)
//   cxyzs   @ 67,371,008 : 16384*16    =    262,144  (ends 67,633,152)
// NEED = 67,633,152 < 75,497,472 (r11-confirmed available).
// Hazards: AN,cxyzs,qkv written(K0) -> AN,cxyzs read(K1), qkv read(K3);
// attnout written(K3) after AN dead; wo(K4) reads attnout. Stream order safe.
// ---------------------------------------------------------------------------
extern "C" void kernel_launch(void* const* d_in, const int* in_sizes, int n_in,
                              void* d_out, int out_size, void* d_ws, size_t ws_size,
                              hipStream_t stream)
{
    const long long want[13] = {4194304LL, 49152LL, 32960LL, 64LL, 64LL,
                                65536LL, 256LL, 65536LL, 256LL,
                                65536LL, 256LL, 65536LL, 256LL};
    int idx[13];
    const int n = n_in;

    const long long* s64 = (const long long*)(const void*)in_sizes;
    const int*       s32 = in_sizes;

    bool ok = false;

    if (n >= 13 && s64[0] == want[0]) {   // int64 interpretation (gated)
        ok = true;
        int walk = 0;
        for (int t = 0; t < 13; t++) {
            int f = -1;
            for (int i = walk; i < n; i++) {
                if (s64[i] == want[t]) { f = i; break; }
            }
            if (f < 0) { ok = false; break; }
            idx[t] = f; walk = f + 1;
        }
    }

    if (!ok) {                            // int32 interpretation
        ok = true;
        int walk = 0;
        for (int t = 0; t < 13; t++) {
            int f = -1;
            for (int i = walk; i < n; i++) {
                if ((long long)s32[i] == want[t]) { f = i; break; }
            }
            if (f < 0) { ok = false; break; }
            idx[t] = f; walk = f + 1;
        }
    }

    if (!ok) return;   // unexpected layout: clean failure, no crash

    const float* tok    = (const float*)d_in[idx[0]];
    const float* coords = (const float*)d_in[idx[1]];
    const float* W1     = (const float*)d_in[idx[2]];
    const float* b1     = (const float*)d_in[idx[3]];
    const float* W2     = (const float*)d_in[idx[4]];
    const float* Wq     = (const float*)d_in[idx[5]];
    const float* bq     = (const float*)d_in[idx[6]];
    const float* Wk     = (const float*)d_in[idx[7]];
    const float* bk     = (const float*)d_in[idx[8]];
    const float* Wv     = (const float*)d_in[idx[9]];
    const float* bv     = (const float*)d_in[idx[10]];
    const float* Wo     = (const float*)d_in[idx[11]];
    const float* bo     = (const float*)d_in[idx[12]];
    float* out = (float*)d_out;

    const size_t NEED = 67633152;
    if (ws_size >= NEED) {
        char* ws = (char*)d_ws;
        int*    sel     = (int*)   (ws + 0);
        float*  AN      = (float*) (ws + 262144);
        float*  attnout = (float*) (ws + 262144);    // aliases AN (dead after K1)
        float*  qkv     = (float*) (ws + 17039360);
        float4* cxyzs   = (float4*)(ws + 67371008);

        qkv_an_gemm_kernel<<<dim3(256, 14), dim3(256), 0, stream>>>(
            tok, Wq, bq, Wk, bk, Wv, bv, W1, coords, qkv, AN, cxyzs);
        knn_score_kernel<<<dim3(2048), dim3(256), 0, stream>>>(AN, cxyzs, W1, b1, W2, sel);
        attn_gather_kernel<<<dim3(16384), dim3(256), 0, stream>>>(qkv, sel, attnout);
        wo_gemm_kernel<<<dim3(256, 4), dim3(256), 0, stream>>>(attnout, Wo, bo, out);
    } else {
        fused_voxel_attn<<<dim3(16384), dim3(256), 0, stream>>>(
            tok, coords, W1, b1, W2, Wq, bq, Wk, bk, Wv, bv, Wo, bo, out, out_size);
    }
}

// Round 11
// 346.133 us; speedup vs baseline: 1.1394x; 1.1009x over previous
//
#include <hip/hip_runtime.h>
#include <hip/hip_bf16.h>

// Problem constants (B=4, V=4096, D=256, H=4, Dh=64, KNN=10, TOPK=4, HID=64)
#define VV 4096
#define DDIM 256
#define KNN_K 10
#define TK 4

// Grid-KNN constants: 16^3 cells over [0,10)^3, cell = 0.625.
// Ring<=2 coverage bound: points outside have d2 >= (2*0.625)^2 = 1.5625.
// Accept threshold 1.54 leaves margin >> fp error (~2e-4) + cell-assign slop.
#define GCELLS 16
#define GINV   1.6f
#define TIER_BNDSQ 1.54f

// fp32 helpers forbidding contraction (bit-faithful np mimicry — DO NOT CHANGE)
__device__ __forceinline__ float f_sq3(float x, float y, float z) {
    return __fadd_rn(__fadd_rn(__fmul_rn(x, x), __fmul_rn(y, y)), __fmul_rn(z, z));
}
__device__ __forceinline__ float f_dot3(float ax, float ay, float az,
                                        float bx, float by, float bz) {
    float d = __fmul_rn(ax, bx);
    d = __fmaf_rn(ay, by, d);
    d = __fmaf_rn(az, bz, d);
    return d;
}

// Monotone float->uint flip: u64 key (flip(d2)<<32)|idx gives EXACT lexicographic
// (d2 float-<, then lowest idx) ordering. d2 is never -0.0 (RN subtract), NaN-free.
__device__ __forceinline__ unsigned long long mkkey(float d2, int j) {
    unsigned u = __float_as_uint(d2);
    u ^= (unsigned)((int)u >> 31) | 0x80000000u;
    return ((unsigned long long)u << 32) | (unsigned)j;
}

// cell index per axis — MUST be identical in build and query
__device__ __forceinline__ int cell1(float x) {
    int c = (int)(x * GINV);
    return c > 15 ? 15 : (c < 0 ? 0 : c);
}

// 4x4 fp32 outer-product accumulate, statically indexed (registers guaranteed)
__device__ __forceinline__ void fma44(const float4 a, const float4 b, float (&c)[4][4]) {
    c[0][0] = fmaf(a.x, b.x, c[0][0]); c[0][1] = fmaf(a.x, b.y, c[0][1]);
    c[0][2] = fmaf(a.x, b.z, c[0][2]); c[0][3] = fmaf(a.x, b.w, c[0][3]);
    c[1][0] = fmaf(a.y, b.x, c[1][0]); c[1][1] = fmaf(a.y, b.y, c[1][1]);
    c[1][2] = fmaf(a.y, b.z, c[1][2]); c[1][3] = fmaf(a.y, b.w, c[1][3]);
    c[2][0] = fmaf(a.z, b.x, c[2][0]); c[2][1] = fmaf(a.z, b.y, c[2][1]);
    c[2][2] = fmaf(a.z, b.z, c[2][2]); c[2][3] = fmaf(a.z, b.w, c[2][3]);
    c[3][0] = fmaf(a.w, b.x, c[3][0]); c[3][1] = fmaf(a.w, b.y, c[3][1]);
    c[3][2] = fmaf(a.w, b.z, c[3][2]); c[3][3] = fmaf(a.w, b.w, c[3][3]);
}

// ===========================================================================
// K-1 (r23 NEW): counting-sort grid build. One block per batch (grid 4).
// cellOff[b][4097] exclusive starts (+end sentinel), sortedIdx[b][4096].
// Within-cell order nondeterministic (atomics) — selection is order-
// independent (unique u64 keys), so results stay deterministic.
// ===========================================================================
__global__ void __launch_bounds__(256) grid_build_kernel(
    const float* __restrict__ coords,
    int* __restrict__ cellOff,
    int* __restrict__ sortedIdx)
{
    const int b   = blockIdx.x;
    const int tid = threadIdx.x;
    const float* cb = coords + (size_t)b * VV * 3;
    int* cOff = cellOff + b * 4097;
    int* sIdx = sortedIdx + b * 4096;

    __shared__ int hist[4096];
    __shared__ int part[256];

    for (int i = tid; i < 4096; i += 256) hist[i] = 0;
    __syncthreads();

    for (int p = tid; p < 4096; p += 256) {
        int c = (cell1(cb[p * 3 + 0]) * 16 + cell1(cb[p * 3 + 1])) * 16 + cell1(cb[p * 3 + 2]);
        atomicAdd(&hist[c], 1);
    }
    __syncthreads();

    // exclusive scan of 4096 bins: 16 serial per thread + block scan of 256
    int loc[16];
    int sum = 0;
    const int bi = tid * 16;
    #pragma unroll
    for (int k = 0; k < 16; k++) { loc[k] = hist[bi + k]; sum += loc[k]; }
    part[tid] = sum;
    __syncthreads();
    for (int off = 1; off < 256; off <<= 1) {
        int vv = (tid >= off) ? part[tid - off] : 0;
        __syncthreads();
        part[tid] += vv;
        __syncthreads();
    }
    int run = part[tid] - sum;      // exclusive base for this thread's 16 bins
    #pragma unroll
    for (int k = 0; k < 16; k++) { int t2 = loc[k]; hist[bi + k] = run; run += t2; }
    __syncthreads();

    for (int i = tid; i < 4096; i += 256) cOff[i] = hist[i];
    if (tid == 0) cOff[4096] = 4096;
    __syncthreads();

    // scatter (hist now running cursors)
    for (int p = tid; p < 4096; p += 256) {
        int c = (cell1(cb[p * 3 + 0]) * 16 + cell1(cb[p * 3 + 1])) * 16 + cell1(cb[p * 3 + 2]);
        int pos = atomicAdd(&hist[c], 1);
        sIdx[pos] = p;
    }
}

// ===========================================================================
// K0 (r20-exact, best measured): merged QKV + AN GEMM at 64x64 tile.
// grid(256,14). Panels 0..11 = Q|K|V; 12..13 = AN halves (bit-identical
// chains). Panel 13 packs cxyzs.
// ===========================================================================
__global__ void __launch_bounds__(256) qkv_an_gemm_kernel(
    const float* __restrict__ tok,
    const float* __restrict__ Wq, const float* __restrict__ bq,
    const float* __restrict__ Wk, const float* __restrict__ bk,
    const float* __restrict__ Wv, const float* __restrict__ bv,
    const float* __restrict__ W1,
    const float* __restrict__ coords,
    float* __restrict__ qkv,
    float* __restrict__ AN,
    float4* __restrict__ cxyzs)
{
    __shared__ float As[16][68];   // [k][m]
    __shared__ float Bs[16][68];   // [k][n]

    const int mBlock = blockIdx.x * 64;
    const int by     = blockIdx.y;            // 0..11 qkv, 12..13 AN
    const int tid    = threadIdx.x;
    const bool isAN  = (by >= 12);
    const int  half  = by - 12;

    if (by == 13 && tid < 64) {
        int m = mBlock + tid;
        float x = coords[m * 3 + 0], y = coords[m * 3 + 1], z = coords[m * 3 + 2];
        cxyzs[m] = make_float4(x, y, z, f_sq3(x, y, z));
    }

    const int nBlock = isAN ? 0 : by * 64;
    const int grp    = isAN ? 0 : (nBlock >> 8);
    const int nIn    = nBlock & 255;
    const float* W    = isAN ? (W1 + (size_t)half * 256 * 64)
                             : ((grp == 0) ? Wq : (grp == 1) ? Wk : Wv);
    const float* bias = (grp == 0) ? bq : (grp == 1) ? bk : bv;

    const int tx = tid & 15;
    const int ty = tid >> 4;
    const int ar  = tid >> 2;
    const int ac4 = tid & 3;
    const int br  = tid >> 4;
    const int bc4 = tid & 15;

    float acc[4][4] = {};

    for (int k0 = 0; k0 < 256; k0 += 16) {
        float4 a4 = *(const float4*)&tok[(size_t)(mBlock + ar) * 256 + k0 + ac4 * 4];
        As[ac4 * 4 + 0][ar] = a4.x;
        As[ac4 * 4 + 1][ar] = a4.y;
        As[ac4 * 4 + 2][ar] = a4.z;
        As[ac4 * 4 + 3][ar] = a4.w;
        float4 b4;
        if (isAN) b4 = *(const float4*)&W[(size_t)(k0 + br) * 64 + bc4 * 4];
        else      b4 = *(const float4*)&W[(size_t)(k0 + br) * 256 + nIn + bc4 * 4];
        *(float4*)&Bs[br][bc4 * 4] = b4;
        __syncthreads();
        #pragma unroll
        for (int kk = 0; kk < 16; kk++) {
            float4 av = *(const float4*)&As[kk][ty * 4];
            float4 bv4 = *(const float4*)&Bs[kk][tx * 4];
            fma44(av, bv4, acc);
        }
        __syncthreads();
    }

    if (!isAN) {
        #pragma unroll
        for (int i = 0; i < 4; i++) {
            int m = mBlock + ty * 4 + i;
            float4 o;
            o.x = acc[i][0] + bias[nIn + tx * 4 + 0];
            o.y = acc[i][1] + bias[nIn + tx * 4 + 1];
            o.z = acc[i][2] + bias[nIn + tx * 4 + 2];
            o.w = acc[i][3] + bias[nIn + tx * 4 + 3];
            *(float4*)&qkv[(size_t)m * 768 + nBlock + tx * 4] = o;
        }
    } else {
        #pragma unroll
        for (int i = 0; i < 4; i++) {
            int m = mBlock + ty * 4 + i;
            float4 o;
            o.x = acc[i][0]; o.y = acc[i][1]; o.z = acc[i][2]; o.w = acc[i][3];
            *(float4*)&AN[(size_t)m * 128 + half * 64 + tx * 4] = o;
        }
    }
}

// ===========================================================================
// K1 (r23): grid-accelerated wave-per-query KNN + score MLP + top-4. grid 4096.
// Tier A: lanes own ring<=2 cells (125 enumerated, lane + lane+64); per-lane
// u64 top-2 with candidate ORDINALS; then r16's exact 11x u64 butterfly
// extraction (unchanged machinery). Bound check certifies exactness
// (d2(11th) < 1.54 < 1.5625-margins => no unscanned point can displace).
// Fallback (rare/never): r16's full 4096-scan VERBATIM => provably
// bit-identical selection on every query. Phase B / scorer unchanged.
// ===========================================================================
__global__ void __launch_bounds__(256) knn_score_kernel(
    const float* __restrict__ AN,
    const float4* __restrict__ cxyzs,
    const int* __restrict__ cellOff,
    const int* __restrict__ sortedIdx,
    const float* __restrict__ W1,
    const float* __restrict__ b1,
    const float* __restrict__ W2,
    int* __restrict__ sel)
{
    const int tid  = threadIdx.x;
    const int lane = tid & 63;
    const int wave = tid >> 6;
    const int q    = blockIdx.x * 4 + wave;   // 0..16383
    const int b    = q >> 12;
    const int base = q & ~4095;
    const int v    = q & 4095;
    const float4* cx = cxyzs + base;
    const int* cOff = cellOff + b * 4097;
    const int* sIdx = sortedIdx + b * 4096;

    __shared__ int   sKnn[4][KNN_K];
    __shared__ float sSc[4][KNN_K];
    __shared__ float sHid[4][KNN_K][65];   // pad 65: scorer stride-65 conflict-free

    float4 cq = cx[v];
    const float qx = cq.x, qy = cq.y, qz = cq.z, sqq = cq.w;
    const int qcx = cell1(qx), qcy = cell1(qy), qcz = cell1(qz);

    // ---------------- Tier A scan: per-lane ring<=2 cells -------------------
    unsigned long long best = ~0ull, second = ~0ull, used = 0ull;
    int bOrd = 0x7fffffff, sOrd = 0x7fffffff;
    int ordEnd = 0;

    #pragma unroll 1
    for (int ci = 0; ci < 2; ci++) {
        int t = lane + ci * 64;
        if (t < 125) {
            int dz = t / 25 - 2;
            int rem = t - (t / 25) * 25;
            int dy = rem / 5 - 2;
            int dx = rem - (rem / 5) * 5 - 2;
            int cxi = qcx + dx, cyi = qcy + dy, czi = qcz + dz;
            if ((unsigned)cxi < 16u && (unsigned)cyi < 16u && (unsigned)czi < 16u) {
                int cell = (cxi * 16 + cyi) * 16 + czi;
                int s = cOff[cell], e = cOff[cell + 1];
                #pragma unroll 1
                for (int p = s; p < e; p++) {
                    int j = sIdx[p];
                    float4 c = cx[j];
                    float dt = f_dot3(qx, qy, qz, c.x, c.y, c.z);
                    float d  = __fsub_rn(__fadd_rn(sqq, c.w), __fmul_rn(2.0f, dt));
                    unsigned long long k = mkkey(d, j);
                    if (k < best)        { second = best; sOrd = bOrd; best = k; bOrd = ordEnd; }
                    else if (k < second) { second = k; sOrd = ordEnd; }
                    ordEnd++;
                }
            }
        }
    }

    bool tierOk = (__ballot(ordEnd > 64) == 0ull);   // used-bitmask capacity

    unsigned long long key11 = ~0ull;
    if (tierOk) {
        // ------------- 11 extractions over tier-A candidates ----------------
        #pragma unroll 1
        for (int it = 0; it < 11; it++) {
            unsigned long long rb = best;
            #pragma unroll
            for (int off = 1; off < 64; off <<= 1) {
                unsigned olo = __shfl_xor((unsigned)rb, off);
                unsigned ohi = __shfl_xor((unsigned)(rb >> 32), off);
                unsigned long long o = ((unsigned long long)ohi << 32) | olo;
                if (o < rb) rb = o;
            }
            int wj = (int)((unsigned)rb & 4095u);
            if (it >= 1 && lane == 0) sKnn[wave][it - 1] = wj;
            if (it == 10) key11 = rb;

            if ((unsigned)best == (unsigned)rb && best != ~0ull) {
                used |= 1ull << bOrd;
                best = second; bOrd = sOrd;
                second = ~0ull; sOrd = 0x7fffffff;
                if (best == ~0ull) {               // rescan lane's cells, skip used ordinals
                    int ord = 0;
                    #pragma unroll 1
                    for (int ci = 0; ci < 2; ci++) {
                        int t = lane + ci * 64;
                        if (t < 125) {
                            int dz = t / 25 - 2;
                            int rem = t - (t / 25) * 25;
                            int dy = rem / 5 - 2;
                            int dx = rem - (rem / 5) * 5 - 2;
                            int cxi = qcx + dx, cyi = qcy + dy, czi = qcz + dz;
                            if ((unsigned)cxi < 16u && (unsigned)cyi < 16u && (unsigned)czi < 16u) {
                                int cell = (cxi * 16 + cyi) * 16 + czi;
                                int s = cOff[cell], e = cOff[cell + 1];
                                #pragma unroll 1
                                for (int p = s; p < e; p++) {
                                    if (!((used >> ord) & 1ull)) {
                                        int j = sIdx[p];
                                        float4 c = cx[j];
                                        float dt = f_dot3(qx, qy, qz, c.x, c.y, c.z);
                                        float d  = __fsub_rn(__fadd_rn(sqq, c.w), __fmul_rn(2.0f, dt));
                                        unsigned long long k = mkkey(d, j);
                                        if (k < best)        { second = best; sOrd = bOrd; best = k; bOrd = ord; }
                                        else if (k < second) { second = k; sOrd = ord; }
                                    }
                                    ord++;
                                }
                            }
                        }
                    }
                }
            }
        }
        // bound certification (wave-uniform): 11 valid AND no unscanned point
        // can beat/tie the 11th (unscanned computed d2 >= 1.5625 - ~2e-4).
        unsigned uu = (unsigned)(key11 >> 32);
        uu = (uu & 0x80000000u) ? (uu ^ 0x80000000u) : ~uu;
        float d11 = __uint_as_float(uu);
        tierOk = (key11 != ~0ull) && (d11 < TIER_BNDSQ);
    }

    if (!tierOk) {
        // ------------- Fallback: r16 full-scan path VERBATIM ----------------
        unsigned long long fb = ~0ull, fs = ~0ull, fused = 0ull;
        #pragma unroll 4
        for (int i = 0; i < 64; i++) {
            int j = i * 64 + lane;
            float4 c = cx[j];
            float dt  = f_dot3(qx, qy, qz, c.x, c.y, c.z);
            float d2v = __fsub_rn(__fadd_rn(sqq, c.w), __fmul_rn(2.0f, dt));
            unsigned long long k = mkkey(d2v, j);
            if (k < fb) { fs = fb; fb = k; }
            else if (k < fs) { fs = k; }
        }
        #pragma unroll 1
        for (int it = 0; it < 11; it++) {
            unsigned long long rb = fb;
            #pragma unroll
            for (int off = 1; off < 64; off <<= 1) {
                unsigned olo = __shfl_xor((unsigned)rb, off);
                unsigned ohi = __shfl_xor((unsigned)(rb >> 32), off);
                unsigned long long o = ((unsigned long long)ohi << 32) | olo;
                if (o < rb) rb = o;
            }
            int wj = (int)((unsigned)rb & 4095u);
            if (it >= 1 && lane == 0) sKnn[wave][it - 1] = wj;
            if ((unsigned)fb == (unsigned)rb) {
                fused |= 1ull << (wj >> 6);
                fb = fs;
                fs = ~0ull;
                if (fb == ~0ull) {
                    #pragma unroll 1
                    for (int i = 0; i < 64; i++) {
                        if ((fused >> i) & 1ull) continue;
                        int j = i * 64 + lane;
                        float4 c = cx[j];
                        float dt  = f_dot3(qx, qy, qz, c.x, c.y, c.z);
                        float d2v = __fsub_rn(__fadd_rn(sqq, c.w), __fmul_rn(2.0f, dt));
                        unsigned long long k = mkkey(d2v, j);
                        if (k < fb) { fs = fb; fb = k; }
                        else if (k < fs) { fs = k; }
                    }
                }
            }
        }
    }

    // ---------------- Phase B: gather-based score MLP (lane == h) ----------
    const float sAl = AN[(size_t)q * 128 + lane];
    const float b1l = b1[lane];
    const float wr0 = W1[(512 + 0) * 64 + lane];
    const float wr1 = W1[(512 + 1) * 64 + lane];
    const float wr2 = W1[(512 + 2) * 64 + lane];

    #pragma unroll 1
    for (int nb = 0; nb < KNN_K; nb++) {
        int kn = sKnn[wave][nb];
        float4 cn = cx[kn];
        float acc = __fadd_rn(sAl, AN[(size_t)(base + kn) * 128 + 64 + lane]);
        float rel0 = __fsub_rn(cn.x, qx);
        acc = __fmaf_rn(rel0, wr0, acc);
        float rel1 = __fsub_rn(cn.y, qy);
        acc = __fmaf_rn(rel1, wr1, acc);
        float rel2 = __fsub_rn(cn.z, qz);
        acc = __fmaf_rn(rel2, wr2, acc);
        float hid = __fadd_rn(acc, b1l);
        sHid[wave][nb][lane] = hid > 0.0f ? hid : 0.0f;
    }

    // sequential-chain scorer, EXACT r13 rounding (lanes 0..9, wave-sync)
    if (lane < KNN_K) {
        float s = 0.0f;
        #pragma unroll 8
        for (int h = 0; h < 64; h++)
            s = __fmaf_rn(sHid[wave][lane][h], W2[h], s);
        sSc[wave][lane] = s;
    }

    if (lane == 0) {          // stable top-4 -> global rows
        unsigned um = 0;
        #pragma unroll
        for (int s = 0; s < TK; s++) {
            float bests = -3.4e38f; int bj = 0;
            for (int jj = 0; jj < KNN_K; jj++) {
                if (um & (1u << jj)) continue;
                float sc = sSc[wave][jj];
                if (sc > bests) { bests = sc; bj = jj; }
            }
            um |= 1u << bj;
            sel[(size_t)q * TK + s] = base + sKnn[wave][bj];
        }
    }
}

// ===========================================================================
// K3 (r0/r13 exact, proven): per-query attention gather. grid 16384.
// ===========================================================================
__global__ void __launch_bounds__(256) attn_gather_kernel(
    const float* __restrict__ qkv, const int* __restrict__ sel,
    float* __restrict__ attnout)
{
    const int q = blockIdx.x;
    const int tid = threadIdx.x;  // = h*64 + dh

    const float qv = qkv[(size_t)q * 768 + tid];

    int rows[TK];
    #pragma unroll
    for (int s = 0; s < TK; s++) rows[s] = sel[(size_t)q * TK + s];

    float att[TK];
    #pragma unroll
    for (int s = 0; s < TK; s++) {
        float p = qv * qkv[(size_t)rows[s] * 768 + 256 + tid];
        #pragma unroll
        for (int m = 1; m < 64; m <<= 1) p += __shfl_xor(p, m);
        att[s] = p * 0.125f;   // 1/sqrt(64)
    }

    float mx  = fmaxf(fmaxf(att[0], att[1]), fmaxf(att[2], att[3]));
    float e0 = expf(att[0] - mx), e1 = expf(att[1] - mx),
          e2 = expf(att[2] - mx), e3 = expf(att[3] - mx);
    float inv = 1.0f / (e0 + e1 + e2 + e3);

    float o = (e0 * qkv[(size_t)rows[0] * 768 + 512 + tid] +
               e1 * qkv[(size_t)rows[1] * 768 + 512 + tid] +
               e2 * qkv[(size_t)rows[2] * 768 + 512 + tid] +
               e3 * qkv[(size_t)rows[3] * 768 + 512 + tid]) * inv;

    attnout[(size_t)q * 256 + tid] = o;
}

// ===========================================================================
// K4 (r0/r13 exact, proven): output projection GEMM 64x64 tile.
// out = attnout @ Wo + bo. M=16384, N=256, K=256. grid(256,4).
// ===========================================================================
__global__ void __launch_bounds__(256) wo_gemm_kernel(
    const float* __restrict__ A,
    const float* __restrict__ Wo, const float* __restrict__ bo,
    float* __restrict__ out)
{
    __shared__ float As[16][68];
    __shared__ float Bs[16][68];

    const int mBlock = blockIdx.x * 64;
    const int nBlock = blockIdx.y * 64;      // 0..192

    const int tid = threadIdx.x;
    const int tx = tid & 15;
    const int ty = tid >> 4;

    const int ar  = tid >> 2;
    const int ac4 = tid & 3;
    const int br  = tid >> 4;
    const int bc4 = tid & 15;

    float acc[4][4] = {};

    for (int k0 = 0; k0 < 256; k0 += 16) {
        float4 a4 = *(const float4*)&A[(size_t)(mBlock + ar) * 256 + k0 + ac4 * 4];
        As[ac4 * 4 + 0][ar] = a4.x;
        As[ac4 * 4 + 1][ar] = a4.y;
        As[ac4 * 4 + 2][ar] = a4.z;
        As[ac4 * 4 + 3][ar] = a4.w;
        float4 b4 = *(const float4*)&Wo[(size_t)(k0 + br) * 256 + nBlock + bc4 * 4];
        *(float4*)&Bs[br][bc4 * 4] = b4;
        __syncthreads();
        #pragma unroll
        for (int kk = 0; kk < 16; kk++) {
            float4 av = *(const float4*)&As[kk][ty * 4];
            float4 bv4 = *(const float4*)&Bs[kk][tx * 4];
            fma44(av, bv4, acc);
        }
        __syncthreads();
    }

    #pragma unroll
    for (int i = 0; i < 4; i++) {
        int m = mBlock + ty * 4 + i;
        float4 o;
        o.x = acc[i][0] + bo[nBlock + tx * 4 + 0];
        o.y = acc[i][1] + bo[nBlock + tx * 4 + 1];
        o.z = acc[i][2] + bo[nBlock + tx * 4 + 2];
        o.w = acc[i][3] + bo[nBlock + tx * 4 + 3];
        *(float4*)&out[(size_t)m * 256 + nBlock + tx * 4] = o;
    }
}

// ===========================================================================
// Fallback: round-9 fully fused kernel (PASSED @1050us), used if ws too small.
// ===========================================================================
__global__ void __launch_bounds__(256) fused_voxel_attn(
    const float* __restrict__ tok,
    const float* __restrict__ coords,
    const float* __restrict__ W1,
    const float* __restrict__ b1,
    const float* __restrict__ W2,
    const float* __restrict__ Wq, const float* __restrict__ bq,
    const float* __restrict__ Wk, const float* __restrict__ bk,
    const float* __restrict__ Wv, const float* __restrict__ bv,
    const float* __restrict__ Wo, const float* __restrict__ bo,
    float* __restrict__ out, int out_size)
{
    const int q    = blockIdx.x;
    const int b    = q >> 12;
    const int v    = q & 4095;
    const int base = q & ~4095;
    const int tid  = threadIdx.x;
    const float* cb = coords + (size_t)b * VV * 3;

    __shared__ float  sval[256];
    __shared__ int    sidx[256];
    __shared__ int    sKnn[KNN_K];
    __shared__ int    sSel[TK];
    __shared__ float  sTokA[DDIM];
    __shared__ float  sTokN[KNN_K][DDIM];
    __shared__ float  sAH[64];
    __shared__ float  sHid[KNN_K][64];
    __shared__ float  sSc[KNN_K];
    __shared__ float  sP[TK][256];
    __shared__ float  sAtt[4][TK];
    __shared__ float  sO[DDIM];

    const float qx = cb[v * 3 + 0];
    const float qy = cb[v * 3 + 1];
    const float qz = cb[v * 3 + 2];
    const float sqq = f_sq3(qx, qy, qz);

    float d2[16];
    #pragma unroll
    for (int i = 0; i < 16; i++) {
        int j = tid + i * 256;
        float xj = cb[j * 3 + 0], yj = cb[j * 3 + 1], zj = cb[j * 3 + 2];
        float sqj = f_sq3(xj, yj, zj);
        float dt  = f_dot3(qx, qy, qz, xj, yj, zj);
        d2[i] = __fsub_rn(__fadd_rn(sqq, sqj), __fmul_rn(2.0f, dt));
    }

    unsigned used = 0;
    for (int it = 0; it < 11; it++) {
        float best = 3.4e38f;
        int bi = 0x7fffffff;
        #pragma unroll
        for (int i = 0; i < 16; i++) {
            if (used & (1u << i)) continue;
            if (d2[i] < best) { best = d2[i]; bi = tid + i * 256; }
        }
        sval[tid] = best;
        sidx[tid] = bi;
        __syncthreads();
        for (int s = 128; s > 0; s >>= 1) {
            if (tid < s) {
                float v2 = sval[tid + s];
                int   i2 = sidx[tid + s];
                if (v2 < sval[tid] || (v2 == sval[tid] && i2 < sidx[tid])) {
                    sval[tid] = v2; sidx[tid] = i2;
                }
            }
            __syncthreads();
        }
        int w = sidx[0] & 4095;
        __syncthreads();
        if (it >= 1 && tid == 0) sKnn[it - 1] = w;
        if ((w & 255) == tid) used |= 1u << (w >> 8);
    }
    __syncthreads();

    sTokA[tid] = tok[(size_t)q * DDIM + tid];
    for (int nb = 0; nb < KNN_K; nb++)
        sTokN[nb][tid] = tok[(size_t)(base + sKnn[nb]) * DDIM + tid];
    __syncthreads();

    if (tid < 64) {
        float a = 0.0f;
        for (int k = 0; k < 256; k++)
            a = __fmaf_rn(sTokA[k], W1[k * 64 + tid], a);
        sAH[tid] = a;
    }
    __syncthreads();

    for (int idx = tid; idx < KNN_K * 64; idx += 256) {
        int nb = idx >> 6;
        int h  = idx & 63;
        float acc = sAH[h];
        const float* tn = sTokN[nb];
        for (int k = 0; k < 256; k++)
            acc = __fmaf_rn(tn[k], W1[(256 + k) * 64 + h], acc);
        #pragma unroll
        for (int c = 0; c < 3; c++) {
            float rel = __fsub_rn(cb[sKnn[nb] * 3 + c], cb[v * 3 + c]);
            acc = __fmaf_rn(rel, W1[(512 + c) * 64 + h], acc);
        }
        float hid = __fadd_rn(acc, b1[h]);
        sHid[nb][h] = hid > 0.0f ? hid : 0.0f;
    }
    __syncthreads();

    if (tid < KNN_K) {
        float s = 0.0f;
        for (int h = 0; h < 64; h++)
            s = __fmaf_rn(sHid[tid][h], W2[h], s);
        sSc[tid] = s;
    }
    __syncthreads();

    if (tid == 0) {
        unsigned um = 0;
        #pragma unroll
        for (int s = 0; s < TK; s++) {
            float best = -3.4e38f; int bj = 0;
            for (int jj = 0; jj < KNN_K; jj++) {
                if (um & (1u << jj)) continue;
                if (sSc[jj] > best) { best = sSc[jj]; bj = jj; }
            }
            um |= 1u << bj;
            sSel[s] = bj;
        }
    }
    __syncthreads();

    int ss[TK];
    float k_acc[TK], v_acc[TK];
    #pragma unroll
    for (int s = 0; s < TK; s++) {
        ss[s] = sSel[s];
        k_acc[s] = bk[tid];
        v_acc[s] = bv[tid];
    }
    float q_acc = bq[tid];

    for (int k = 0; k < 256; k++) {
        float wq = Wq[k * 256 + tid];
        float wk = Wk[k * 256 + tid];
        float wv = Wv[k * 256 + tid];
        q_acc += sTokA[k] * wq;
        #pragma unroll
        for (int s = 0; s < TK; s++) {
            float x = sTokN[ss[s]][k];
            k_acc[s] += x * wk;
            v_acc[s] += x * wv;
        }
    }

    #pragma unroll
    for (int s = 0; s < TK; s++) sP[s][tid] = q_acc * k_acc[s];
    __syncthreads();

    if (tid < 16) {
        int h = tid >> 2, s = tid & 3;
        float p = 0.0f;
        for (int d = 0; d < 64; d++) p += sP[s][h * 64 + d];
        sAtt[h][s] = p * 0.125f;
    }
    __syncthreads();

    const int hh = tid >> 6;
    float a0 = sAtt[hh][0], a1 = sAtt[hh][1], a2 = sAtt[hh][2], a3 = sAtt[hh][3];
    float mx  = fmaxf(fmaxf(a0, a1), fmaxf(a2, a3));
    float e0 = expf(a0 - mx), e1 = expf(a1 - mx), e2 = expf(a2 - mx), e3 = expf(a3 - mx);
    float inv = 1.0f / (e0 + e1 + e2 + e3);
    float o = (e0 * v_acc[0] + e1 * v_acc[1] + e2 * v_acc[2] + e3 * v_acc[3]) * inv;

    sO[tid] = o;
    __syncthreads();

    float a = bo[tid];
    for (int e = 0; e < 256; e++) a += sO[e] * Wo[e * 256 + tid];
    int oidx = q * DDIM + tid;
    if (oidx < out_size)
        out[oidx] = a;
}

// ---------------------------------------------------------------------------
// Launcher. ABI-bilingual size-walk (validated r8-r11). r23 ws layout:
//   sel       @ 0          : 16384*4*4   =    262,144
//   AN        @ 262,144    : 16384*128*4 =  8,388,608  (ends  8,650,752)
//   attnout   @ 262,144    : 16384*256*4 = 16,777,216  (ends 17,039,360) ALIAS of AN
//   qkv       @ 17,039,360 : 16384*768*4 = 50,331,648  (ends 67,371,008)
//   cxyzs     @ 67,371,008 : 16384*16    =    262,144  (ends 67,633,152)
//   cellOff   @ 67,633,152 : 4*4097*4    =     65,552  (ends 67,698,704)
//   sortedIdx @ 67,698,704 : 4*4096*4    =     65,536  (ends 67,764,240)
// NEED = 67,764,240 < 75,497,472 (r11-confirmed available).
// Order: grid_build (coords) -> qkv_an (cxyzs/AN/qkv) -> knn (grid+cxyzs+AN)
// -> attn (qkv+sel) -> wo. Same-stream order guarantees safety.
// ---------------------------------------------------------------------------
extern "C" void kernel_launch(void* const* d_in, const int* in_sizes, int n_in,
                              void* d_out, int out_size, void* d_ws, size_t ws_size,
                              hipStream_t stream)
{
    const long long want[13] = {4194304LL, 49152LL, 32960LL, 64LL, 64LL,
                                65536LL, 256LL, 65536LL, 256LL,
                                65536LL, 256LL, 65536LL, 256LL};
    int idx[13];
    const int n = n_in;

    const long long* s64 = (const long long*)(const void*)in_sizes;
    const int*       s32 = in_sizes;

    bool ok = false;

    if (n >= 13 && s64[0] == want[0]) {   // int64 interpretation (gated)
        ok = true;
        int walk = 0;
        for (int t = 0; t < 13; t++) {
            int f = -1;
            for (int i = walk; i < n; i++) {
                if (s64[i] == want[t]) { f = i; break; }
            }
            if (f < 0) { ok = false; break; }
            idx[t] = f; walk = f + 1;
        }
    }

    if (!ok) {                            // int32 interpretation
        ok = true;
        int walk = 0;
        for (int t = 0; t < 13; t++) {
            int f = -1;
            for (int i = walk; i < n; i++) {
                if ((long long)s32[i] == want[t]) { f = i; break; }
            }
            if (f < 0) { ok = false; break; }
            idx[t] = f; walk = f + 1;
        }
    }

    if (!ok) return;   // unexpected layout: clean failure, no crash

    const float* tok    = (const float*)d_in[idx[0]];
    const float* coords = (const float*)d_in[idx[1]];
    const float* W1     = (const float*)d_in[idx[2]];
    const float* b1     = (const float*)d_in[idx[3]];
    const float* W2     = (const float*)d_in[idx[4]];
    const float* Wq     = (const float*)d_in[idx[5]];
    const float* bq     = (const float*)d_in[idx[6]];
    const float* Wk     = (const float*)d_in[idx[7]];
    const float* bk     = (const float*)d_in[idx[8]];
    const float* Wv     = (const float*)d_in[idx[9]];
    const float* bv     = (const float*)d_in[idx[10]];
    const float* Wo     = (const float*)d_in[idx[11]];
    const float* bo     = (const float*)d_in[idx[12]];
    float* out = (float*)d_out;

    const size_t NEED = 67764240;
    if (ws_size >= NEED) {
        char* ws = (char*)d_ws;
        int*    sel     = (int*)   (ws + 0);
        float*  AN      = (float*) (ws + 262144);
        float*  attnout = (float*) (ws + 262144);    // aliases AN (dead after K1)
        float*  qkv     = (float*) (ws + 17039360);
        float4* cxyzs   = (float4*)(ws + 67371008);
        int*    cellOff = (int*)   (ws + 67633152);
        int*    sortIdx = (int*)   (ws + 67698704);

        grid_build_kernel<<<dim3(4), dim3(256), 0, stream>>>(coords, cellOff, sortIdx);
        qkv_an_gemm_kernel<<<dim3(256, 14), dim3(256), 0, stream>>>(
            tok, Wq, bq, Wk, bk, Wv, bv, W1, coords, qkv, AN, cxyzs);
        knn_score_kernel<<<dim3(4096), dim3(256), 0, stream>>>(
            AN, cxyzs, cellOff, sortIdx, W1, b1, W2, sel);
        attn_gather_kernel<<<dim3(16384), dim3(256), 0, stream>>>(qkv, sel, attnout);
        wo_gemm_kernel<<<dim3(256, 4), dim3(256), 0, stream>>>(attnout, Wo, bo, out);
    } else {
        fused_voxel_attn<<<dim3(16384), dim3(256), 0, stream>>>(
            tok, coords, W1, b1, W2, Wq, bq, Wk, bk, Wv, bv, Wo, bo, out, out_size);
    }
}

// Round 13
// 337.084 us; speedup vs baseline: 1.1700x; 1.0268x over previous
//
#include <hip/hip_runtime.h>
#include <hip/hip_bf16.h>

// Problem constants (B=4, V=4096, D=256, H=4, Dh=64, KNN=10, TOPK=4, HID=64)
#define VV 4096
#define DDIM 256
#define KNN_K 10
#define TK 4

// Grid-KNN constants: 16^3 cells over [0,10)^3, cell = 0.625.
// Ring<=2 coverage bound: points outside have d2 >= (2*0.625)^2 = 1.5625.
// Accept threshold 1.54 leaves margin >> fp error (~2e-4) + cell-assign slop.
#define GCELLS 16
#define GINV   1.6f
#define TIER_BNDSQ 1.54f

// fp32 helpers forbidding contraction (bit-faithful np mimicry — DO NOT CHANGE)
__device__ __forceinline__ float f_sq3(float x, float y, float z) {
    return __fadd_rn(__fadd_rn(__fmul_rn(x, x), __fmul_rn(y, y)), __fmul_rn(z, z));
}
__device__ __forceinline__ float f_dot3(float ax, float ay, float az,
                                        float bx, float by, float bz) {
    float d = __fmul_rn(ax, bx);
    d = __fmaf_rn(ay, by, d);
    d = __fmaf_rn(az, bz, d);
    return d;
}

// Monotone float->uint flip: u64 key (flip(d2)<<32)|idx gives EXACT lexicographic
// (d2 float-<, then lowest idx) ordering. d2 is never -0.0 (RN subtract), NaN-free.
__device__ __forceinline__ unsigned long long mkkey(float d2, int j) {
    unsigned u = __float_as_uint(d2);
    u ^= (unsigned)((int)u >> 31) | 0x80000000u;
    return ((unsigned long long)u << 32) | (unsigned)j;
}

// cell index per axis — MUST be identical in build and query
__device__ __forceinline__ int cell1(float x) {
    int c = (int)(x * GINV);
    return c > 15 ? 15 : (c < 0 ? 0 : c);
}

// 4x4 fp32 outer-product accumulate, statically indexed (registers guaranteed)
__device__ __forceinline__ void fma44(const float4 a, const float4 b, float (&c)[4][4]) {
    c[0][0] = fmaf(a.x, b.x, c[0][0]); c[0][1] = fmaf(a.x, b.y, c[0][1]);
    c[0][2] = fmaf(a.x, b.z, c[0][2]); c[0][3] = fmaf(a.x, b.w, c[0][3]);
    c[1][0] = fmaf(a.y, b.x, c[1][0]); c[1][1] = fmaf(a.y, b.y, c[1][1]);
    c[1][2] = fmaf(a.y, b.z, c[1][2]); c[1][3] = fmaf(a.y, b.w, c[1][3]);
    c[2][0] = fmaf(a.z, b.x, c[2][0]); c[2][1] = fmaf(a.z, b.y, c[2][1]);
    c[2][2] = fmaf(a.z, b.z, c[2][2]); c[2][3] = fmaf(a.z, b.w, c[2][3]);
    c[3][0] = fmaf(a.w, b.x, c[3][0]); c[3][1] = fmaf(a.w, b.y, c[3][1]);
    c[3][2] = fmaf(a.w, b.z, c[3][2]); c[3][3] = fmaf(a.w, b.w, c[3][3]);
}

// ===========================================================================
// K-1 (r23, proven): counting-sort grid build. One block per batch (grid 4).
// ===========================================================================
__global__ void __launch_bounds__(256) grid_build_kernel(
    const float* __restrict__ coords,
    int* __restrict__ cellOff,
    int* __restrict__ sortedIdx)
{
    const int b   = blockIdx.x;
    const int tid = threadIdx.x;
    const float* cb = coords + (size_t)b * VV * 3;
    int* cOff = cellOff + b * 4097;
    int* sIdx = sortedIdx + b * 4096;

    __shared__ int hist[4096];
    __shared__ int part[256];

    for (int i = tid; i < 4096; i += 256) hist[i] = 0;
    __syncthreads();

    for (int p = tid; p < 4096; p += 256) {
        int c = (cell1(cb[p * 3 + 0]) * 16 + cell1(cb[p * 3 + 1])) * 16 + cell1(cb[p * 3 + 2]);
        atomicAdd(&hist[c], 1);
    }
    __syncthreads();

    int loc[16];
    int sum = 0;
    const int bi = tid * 16;
    #pragma unroll
    for (int k = 0; k < 16; k++) { loc[k] = hist[bi + k]; sum += loc[k]; }
    part[tid] = sum;
    __syncthreads();
    for (int off = 1; off < 256; off <<= 1) {
        int vv = (tid >= off) ? part[tid - off] : 0;
        __syncthreads();
        part[tid] += vv;
        __syncthreads();
    }
    int run = part[tid] - sum;
    #pragma unroll
    for (int k = 0; k < 16; k++) { int t2 = loc[k]; hist[bi + k] = run; run += t2; }
    __syncthreads();

    for (int i = tid; i < 4096; i += 256) cOff[i] = hist[i];
    if (tid == 0) cOff[4096] = 4096;
    __syncthreads();

    for (int p = tid; p < 4096; p += 256) {
        int c = (cell1(cb[p * 3 + 0]) * 16 + cell1(cb[p * 3 + 1])) * 16 + cell1(cb[p * 3 + 2]);
        int pos = atomicAdd(&hist[c], 1);
        sIdx[pos] = p;
    }
}

// ===========================================================================
// K0 (r24): merged QKV + AN GEMM, 128x64 tile / 8x4 per thread. grid(128,14).
// Per kk: 32 FMA vs 3 ds_read_b128 (vs 64^2 tile's 16 FMA / 2 reads) — halves
// DS-pipe load per FLOP (r23 PMC: VALUBusy 78% but only 39% peak, DS-bound).
// Only 32 acc VGPRs (vs r19's 64 @128x128 disaster); no launch_bounds
// override. Per-output fmaf chain over ascending k unchanged => qkv/AN
// bit-identical. Panel 13 packs cxyzs (tid<128, 128 blocks).
// ===========================================================================
__global__ void __launch_bounds__(256) qkv_an_gemm_kernel(
    const float* __restrict__ tok,
    const float* __restrict__ Wq, const float* __restrict__ bq,
    const float* __restrict__ Wk, const float* __restrict__ bk,
    const float* __restrict__ Wv, const float* __restrict__ bv,
    const float* __restrict__ W1,
    const float* __restrict__ coords,
    float* __restrict__ qkv,
    float* __restrict__ AN,
    float4* __restrict__ cxyzs)
{
    __shared__ float As[16][132];   // [k][m: 128 + pad]
    __shared__ float Bs[16][68];    // [k][n: 64 + pad]

    const int mBlock = blockIdx.x * 128;
    const int by     = blockIdx.y;            // 0..11 qkv, 12..13 AN
    const int tid    = threadIdx.x;
    const bool isAN  = (by >= 12);
    const int  half  = by - 12;

    // side job (panel 13): packed coords + squared norm (bit-identical f_sq3)
    if (by == 13 && tid < 128) {
        int m = mBlock + tid;
        float x = coords[m * 3 + 0], y = coords[m * 3 + 1], z = coords[m * 3 + 2];
        cxyzs[m] = make_float4(x, y, z, f_sq3(x, y, z));
    }

    const int nBlock = isAN ? 0 : by * 64;
    const int grp    = isAN ? 0 : (nBlock >> 8);
    const int nIn    = nBlock & 255;
    const float* W    = isAN ? (W1 + (size_t)half * 256 * 64)
                             : ((grp == 0) ? Wq : (grp == 1) ? Wk : Wv);
    const float* bias = (grp == 0) ? bq : (grp == 1) ? bk : bv;

    const int tx = tid & 15;     // n-dir: 4 cols
    const int ty = tid >> 4;     // m-dir: 0..15, 8 rows each

    const int ar  = tid >> 2;          // 0..63 (A stage row; +64 second half)
    const int ac4 = tid & 3;           // 0..3  (k float4)
    const int br  = tid >> 4;          // 0..15 (B k row)
    const int bc4 = tid & 15;          // 0..15 (B n float4)

    float acc0[4][4] = {};   // rows ty*8 .. ty*8+3
    float acc1[4][4] = {};   // rows ty*8+4 .. ty*8+7

    for (int k0 = 0; k0 < 256; k0 += 16) {
        float4 a0 = *(const float4*)&tok[(size_t)(mBlock + ar) * 256 + k0 + ac4 * 4];
        float4 a1 = *(const float4*)&tok[(size_t)(mBlock + 64 + ar) * 256 + k0 + ac4 * 4];
        As[ac4 * 4 + 0][ar] = a0.x;      As[ac4 * 4 + 0][64 + ar] = a1.x;
        As[ac4 * 4 + 1][ar] = a0.y;      As[ac4 * 4 + 1][64 + ar] = a1.y;
        As[ac4 * 4 + 2][ar] = a0.z;      As[ac4 * 4 + 2][64 + ar] = a1.z;
        As[ac4 * 4 + 3][ar] = a0.w;      As[ac4 * 4 + 3][64 + ar] = a1.w;
        float4 b4;
        if (isAN) b4 = *(const float4*)&W[(size_t)(k0 + br) * 64 + bc4 * 4];
        else      b4 = *(const float4*)&W[(size_t)(k0 + br) * 256 + nIn + bc4 * 4];
        *(float4*)&Bs[br][bc4 * 4] = b4;
        __syncthreads();
        #pragma unroll
        for (int kk = 0; kk < 16; kk++) {
            float4 av0 = *(const float4*)&As[kk][ty * 8];
            float4 av1 = *(const float4*)&As[kk][ty * 8 + 4];
            float4 bv4 = *(const float4*)&Bs[kk][tx * 4];
            fma44(av0, bv4, acc0);
            fma44(av1, bv4, acc1);
        }
        __syncthreads();
    }

    if (!isAN) {
        #pragma unroll
        for (int i = 0; i < 4; i++) {
            int m0 = mBlock + ty * 8 + i;
            int m1 = m0 + 4;
            float4 o;
            o.x = acc0[i][0] + bias[nIn + tx * 4 + 0];
            o.y = acc0[i][1] + bias[nIn + tx * 4 + 1];
            o.z = acc0[i][2] + bias[nIn + tx * 4 + 2];
            o.w = acc0[i][3] + bias[nIn + tx * 4 + 3];
            *(float4*)&qkv[(size_t)m0 * 768 + nBlock + tx * 4] = o;
            o.x = acc1[i][0] + bias[nIn + tx * 4 + 0];
            o.y = acc1[i][1] + bias[nIn + tx * 4 + 1];
            o.z = acc1[i][2] + bias[nIn + tx * 4 + 2];
            o.w = acc1[i][3] + bias[nIn + tx * 4 + 3];
            *(float4*)&qkv[(size_t)m1 * 768 + nBlock + tx * 4] = o;
        }
    } else {
        #pragma unroll
        for (int i = 0; i < 4; i++) {
            int m0 = mBlock + ty * 8 + i;
            int m1 = m0 + 4;
            float4 o;
            o.x = acc0[i][0]; o.y = acc0[i][1]; o.z = acc0[i][2]; o.w = acc0[i][3];
            *(float4*)&AN[(size_t)m0 * 128 + half * 64 + tx * 4] = o;
            o.x = acc1[i][0]; o.y = acc1[i][1]; o.z = acc1[i][2]; o.w = acc1[i][3];
            *(float4*)&AN[(size_t)m1 * 128 + half * 64 + tx * 4] = o;
        }
    }
}

// ===========================================================================
// K1 (r23, proven): grid-accelerated wave-per-query KNN + score MLP + top-4.
// grid 4096. Tier A ring<=2 scan + exact u64 extraction + bound
// certification; verbatim r16 full-scan fallback => bit-identical selection.
// ===========================================================================
__global__ void __launch_bounds__(256) knn_score_kernel(
    const float* __restrict__ AN,
    const float4* __restrict__ cxyzs,
    const int* __restrict__ cellOff,
    const int* __restrict__ sortedIdx,
    const float* __restrict__ W1,
    const float* __restrict__ b1,
    const float* __restrict__ W2,
    int* __restrict__ sel)
{
    const int tid  = threadIdx.x;
    const int lane = tid & 63;
    const int wave = tid >> 6;
    const int q    = blockIdx.x * 4 + wave;   // 0..16383
    const int b    = q >> 12;
    const int base = q & ~4095;
    const int v    = q & 4095;
    const float4* cx = cxyzs + base;
    const int* cOff = cellOff + b * 4097;
    const int* sIdx = sortedIdx + b * 4096;

    __shared__ int   sKnn[4][KNN_K];
    __shared__ float sSc[4][KNN_K];
    __shared__ float sHid[4][KNN_K][65];   // pad 65: scorer stride-65 conflict-free

    float4 cq = cx[v];
    const float qx = cq.x, qy = cq.y, qz = cq.z, sqq = cq.w;
    const int qcx = cell1(qx), qcy = cell1(qy), qcz = cell1(qz);

    // ---------------- Tier A scan: per-lane ring<=2 cells -------------------
    unsigned long long best = ~0ull, second = ~0ull, used = 0ull;
    int bOrd = 0x7fffffff, sOrd = 0x7fffffff;
    int ordEnd = 0;

    #pragma unroll 1
    for (int ci = 0; ci < 2; ci++) {
        int t = lane + ci * 64;
        if (t < 125) {
            int dz = t / 25 - 2;
            int rem = t - (t / 25) * 25;
            int dy = rem / 5 - 2;
            int dx = rem - (rem / 5) * 5 - 2;
            int cxi = qcx + dx, cyi = qcy + dy, czi = qcz + dz;
            if ((unsigned)cxi < 16u && (unsigned)cyi < 16u && (unsigned)czi < 16u) {
                int cell = (cxi * 16 + cyi) * 16 + czi;
                int s = cOff[cell], e = cOff[cell + 1];
                #pragma unroll 1
                for (int p = s; p < e; p++) {
                    int j = sIdx[p];
                    float4 c = cx[j];
                    float dt = f_dot3(qx, qy, qz, c.x, c.y, c.z);
                    float d  = __fsub_rn(__fadd_rn(sqq, c.w), __fmul_rn(2.0f, dt));
                    unsigned long long k = mkkey(d, j);
                    if (k < best)        { second = best; sOrd = bOrd; best = k; bOrd = ordEnd; }
                    else if (k < second) { second = k; sOrd = ordEnd; }
                    ordEnd++;
                }
            }
        }
    }

    bool tierOk = (__ballot(ordEnd > 64) == 0ull);   // used-bitmask capacity

    unsigned long long key11 = ~0ull;
    if (tierOk) {
        #pragma unroll 1
        for (int it = 0; it < 11; it++) {
            unsigned long long rb = best;
            #pragma unroll
            for (int off = 1; off < 64; off <<= 1) {
                unsigned olo = __shfl_xor((unsigned)rb, off);
                unsigned ohi = __shfl_xor((unsigned)(rb >> 32), off);
                unsigned long long o = ((unsigned long long)ohi << 32) | olo;
                if (o < rb) rb = o;
            }
            int wj = (int)((unsigned)rb & 4095u);
            if (it >= 1 && lane == 0) sKnn[wave][it - 1] = wj;
            if (it == 10) key11 = rb;

            if ((unsigned)best == (unsigned)rb && best != ~0ull) {
                used |= 1ull << bOrd;
                best = second; bOrd = sOrd;
                second = ~0ull; sOrd = 0x7fffffff;
                if (best == ~0ull) {               // rescan lane's cells, skip used ordinals
                    int ord = 0;
                    #pragma unroll 1
                    for (int ci = 0; ci < 2; ci++) {
                        int t = lane + ci * 64;
                        if (t < 125) {
                            int dz = t / 25 - 2;
                            int rem = t - (t / 25) * 25;
                            int dy = rem / 5 - 2;
                            int dx = rem - (rem / 5) * 5 - 2;
                            int cxi = qcx + dx, cyi = qcy + dy, czi = qcz + dz;
                            if ((unsigned)cxi < 16u && (unsigned)cyi < 16u && (unsigned)czi < 16u) {
                                int cell = (cxi * 16 + cyi) * 16 + czi;
                                int s = cOff[cell], e = cOff[cell + 1];
                                #pragma unroll 1
                                for (int p = s; p < e; p++) {
                                    if (!((used >> ord) & 1ull)) {
                                        int j = sIdx[p];
                                        float4 c = cx[j];
                                        float dt = f_dot3(qx, qy, qz, c.x, c.y, c.z);
                                        float d  = __fsub_rn(__fadd_rn(sqq, c.w), __fmul_rn(2.0f, dt));
                                        unsigned long long k = mkkey(d, j);
                                        if (k < best)        { second = best; sOrd = bOrd; best = k; bOrd = ord; }
                                        else if (k < second) { second = k; sOrd = ord; }
                                    }
                                    ord++;
                                }
                            }
                        }
                    }
                }
            }
        }
        unsigned uu = (unsigned)(key11 >> 32);
        uu = (uu & 0x80000000u) ? (uu ^ 0x80000000u) : ~uu;
        float d11 = __uint_as_float(uu);
        tierOk = (key11 != ~0ull) && (d11 < TIER_BNDSQ);
    }

    if (!tierOk) {
        // ------------- Fallback: r16 full-scan path VERBATIM ----------------
        unsigned long long fb = ~0ull, fs = ~0ull, fused = 0ull;
        #pragma unroll 4
        for (int i = 0; i < 64; i++) {
            int j = i * 64 + lane;
            float4 c = cx[j];
            float dt  = f_dot3(qx, qy, qz, c.x, c.y, c.z);
            float d2v = __fsub_rn(__fadd_rn(sqq, c.w), __fmul_rn(2.0f, dt));
            unsigned long long k = mkkey(d2v, j);
            if (k < fb) { fs = fb; fb = k; }
            else if (k < fs) { fs = k; }
        }
        #pragma unroll 1
        for (int it = 0; it < 11; it++) {
            unsigned long long rb = fb;
            #pragma unroll
            for (int off = 1; off < 64; off <<= 1) {
                unsigned olo = __shfl_xor((unsigned)rb, off);
                unsigned ohi = __shfl_xor((unsigned)(rb >> 32), off);
                unsigned long long o = ((unsigned long long)ohi << 32) | olo;
                if (o < rb) rb = o;
            }
            int wj = (int)((unsigned)rb & 4095u);
            if (it >= 1 && lane == 0) sKnn[wave][it - 1] = wj;
            if ((unsigned)fb == (unsigned)rb) {
                fused |= 1ull << (wj >> 6);
                fb = fs;
                fs = ~0ull;
                if (fb == ~0ull) {
                    #pragma unroll 1
                    for (int i = 0; i < 64; i++) {
                        if ((fused >> i) & 1ull) continue;
                        int j = i * 64 + lane;
                        float4 c = cx[j];
                        float dt  = f_dot3(qx, qy, qz, c.x, c.y, c.z);
                        float d2v = __fsub_rn(__fadd_rn(sqq, c.w), __fmul_rn(2.0f, dt));
                        unsigned long long k = mkkey(d2v, j);
                        if (k < fb) { fs = fb; fb = k; }
                        else if (k < fs) { fs = k; }
                    }
                }
            }
        }
    }

    // ---------------- Phase B: gather-based score MLP (lane == h) ----------
    const float sAl = AN[(size_t)q * 128 + lane];
    const float b1l = b1[lane];
    const float wr0 = W1[(512 + 0) * 64 + lane];
    const float wr1 = W1[(512 + 1) * 64 + lane];
    const float wr2 = W1[(512 + 2) * 64 + lane];

    #pragma unroll 1
    for (int nb = 0; nb < KNN_K; nb++) {
        int kn = sKnn[wave][nb];
        float4 cn = cx[kn];
        float acc = __fadd_rn(sAl, AN[(size_t)(base + kn) * 128 + 64 + lane]);
        float rel0 = __fsub_rn(cn.x, qx);
        acc = __fmaf_rn(rel0, wr0, acc);
        float rel1 = __fsub_rn(cn.y, qy);
        acc = __fmaf_rn(rel1, wr1, acc);
        float rel2 = __fsub_rn(cn.z, qz);
        acc = __fmaf_rn(rel2, wr2, acc);
        float hid = __fadd_rn(acc, b1l);
        sHid[wave][nb][lane] = hid > 0.0f ? hid : 0.0f;
    }

    // sequential-chain scorer, EXACT r13 rounding (lanes 0..9, wave-sync)
    if (lane < KNN_K) {
        float s = 0.0f;
        #pragma unroll 8
        for (int h = 0; h < 64; h++)
            s = __fmaf_rn(sHid[wave][lane][h], W2[h], s);
        sSc[wave][lane] = s;
    }

    if (lane == 0) {          // stable top-4 -> global rows
        unsigned um = 0;
        #pragma unroll
        for (int s = 0; s < TK; s++) {
            float bests = -3.4e38f; int bj = 0;
            for (int jj = 0; jj < KNN_K; jj++) {
                if (um & (1u << jj)) continue;
                float sc = sSc[wave][jj];
                if (sc > bests) { bests = sc; bj = jj; }
            }
            um |= 1u << bj;
            sel[(size_t)q * TK + s] = base + sKnn[wave][bj];
        }
    }
}

// ===========================================================================
// K3 (r0/r13 exact, proven): per-query attention gather. grid 16384.
// ===========================================================================
__global__ void __launch_bounds__(256) attn_gather_kernel(
    const float* __restrict__ qkv, const int* __restrict__ sel,
    float* __restrict__ attnout)
{
    const int q = blockIdx.x;
    const int tid = threadIdx.x;  // = h*64 + dh

    const float qv = qkv[(size_t)q * 768 + tid];

    int rows[TK];
    #pragma unroll
    for (int s = 0; s < TK; s++) rows[s] = sel[(size_t)q * TK + s];

    float att[TK];
    #pragma unroll
    for (int s = 0; s < TK; s++) {
        float p = qv * qkv[(size_t)rows[s] * 768 + 256 + tid];
        #pragma unroll
        for (int m = 1; m < 64; m <<= 1) p += __shfl_xor(p, m);
        att[s] = p * 0.125f;   // 1/sqrt(64)
    }

    float mx  = fmaxf(fmaxf(att[0], att[1]), fmaxf(att[2], att[3]));
    float e0 = expf(att[0] - mx), e1 = expf(att[1] - mx),
          e2 = expf(att[2] - mx), e3 = expf(att[3] - mx);
    float inv = 1.0f / (e0 + e1 + e2 + e3);

    float o = (e0 * qkv[(size_t)rows[0] * 768 + 512 + tid] +
               e1 * qkv[(size_t)rows[1] * 768 + 512 + tid] +
               e2 * qkv[(size_t)rows[2] * 768 + 512 + tid] +
               e3 * qkv[(size_t)rows[3] * 768 + 512 + tid]) * inv;

    attnout[(size_t)q * 256 + tid] = o;
}

// ===========================================================================
// K4 (r24): output projection GEMM, 128x64 tile / 8x4 per thread. grid(128,4).
// Same DS-pressure fix as K0; per-output fmaf chain unchanged (bit-identical).
// ===========================================================================
__global__ void __launch_bounds__(256) wo_gemm_kernel(
    const float* __restrict__ A,
    const float* __restrict__ Wo, const float* __restrict__ bo,
    float* __restrict__ out)
{
    __shared__ float As[16][132];
    __shared__ float Bs[16][68];

    const int mBlock = blockIdx.x * 128;
    const int nBlock = blockIdx.y * 64;      // 0..192

    const int tid = threadIdx.x;
    const int tx = tid & 15;
    const int ty = tid >> 4;

    const int ar  = tid >> 2;
    const int ac4 = tid & 3;
    const int br  = tid >> 4;
    const int bc4 = tid & 15;

    float acc0[4][4] = {};
    float acc1[4][4] = {};

    for (int k0 = 0; k0 < 256; k0 += 16) {
        float4 a0 = *(const float4*)&A[(size_t)(mBlock + ar) * 256 + k0 + ac4 * 4];
        float4 a1 = *(const float4*)&A[(size_t)(mBlock + 64 + ar) * 256 + k0 + ac4 * 4];
        As[ac4 * 4 + 0][ar] = a0.x;      As[ac4 * 4 + 0][64 + ar] = a1.x;
        As[ac4 * 4 + 1][ar] = a0.y;      As[ac4 * 4 + 1][64 + ar] = a1.y;
        As[ac4 * 4 + 2][ar] = a0.z;      As[ac4 * 4 + 2][64 + ar] = a1.z;
        As[ac4 * 4 + 3][ar] = a0.w;      As[ac4 * 4 + 3][64 + ar] = a1.w;
        float4 b4 = *(const float4*)&Wo[(size_t)(k0 + br) * 256 + nBlock + bc4 * 4];
        *(float4*)&Bs[br][bc4 * 4] = b4;
        __syncthreads();
        #pragma unroll
        for (int kk = 0; kk < 16; kk++) {
            float4 av0 = *(const float4*)&As[kk][ty * 8];
            float4 av1 = *(const float4*)&As[kk][ty * 8 + 4];
            float4 bv4 = *(const float4*)&Bs[kk][tx * 4];
            fma44(av0, bv4, acc0);
            fma44(av1, bv4, acc1);
        }
        __syncthreads();
    }

    #pragma unroll
    for (int i = 0; i < 4; i++) {
        int m0 = mBlock + ty * 8 + i;
        int m1 = m0 + 4;
        float4 o;
        o.x = acc0[i][0] + bo[nBlock + tx * 4 + 0];
        o.y = acc0[i][1] + bo[nBlock + tx * 4 + 1];
        o.z = acc0[i][2] + bo[nBlock + tx * 4 + 2];
        o.w = acc0[i][3] + bo[nBlock + tx * 4 + 3];
        *(float4*)&out[(size_t)m0 * 256 + nBlock + tx * 4] = o;
        o.x = acc1[i][0] + bo[nBlock + tx * 4 + 0];
        o.y = acc1[i][1] + bo[nBlock + tx * 4 + 1];
        o.z = acc1[i][2] + bo[nBlock + tx * 4 + 2];
        o.w = acc1[i][3] + bo[nBlock + tx * 4 + 3];
        *(float4*)&out[(size_t)m1 * 256 + nBlock + tx * 4] = o;
    }
}

// ===========================================================================
// Fallback: round-9 fully fused kernel (PASSED @1050us), used if ws too small.
// ===========================================================================
__global__ void __launch_bounds__(256) fused_voxel_attn(
    const float* __restrict__ tok,
    const float* __restrict__ coords,
    const float* __restrict__ W1,
    const float* __restrict__ b1,
    const float* __restrict__ W2,
    const float* __restrict__ Wq, const float* __restrict__ bq,
    const float* __restrict__ Wk, const float* __restrict__ bk,
    const float* __restrict__ Wv, const float* __restrict__ bv,
    const float* __restrict__ Wo, const float* __restrict__ bo,
    float* __restrict__ out, int out_size)
{
    const int q    = blockIdx.x;
    const int b    = q >> 12;
    const int v    = q & 4095;
    const int base = q & ~4095;
    const int tid  = threadIdx.x;
    const float* cb = coords + (size_t)b * VV * 3;

    __shared__ float  sval[256];
    __shared__ int    sidx[256];
    __shared__ int    sKnn[KNN_K];
    __shared__ int    sSel[TK];
    __shared__ float  sTokA[DDIM];
    __shared__ float  sTokN[KNN_K][DDIM];
    __shared__ float  sAH[64];
    __shared__ float  sHid[KNN_K][64];
    __shared__ float  sSc[KNN_K];
    __shared__ float  sP[TK][256];
    __shared__ float  sAtt[4][TK];
    __shared__ float  sO[DDIM];

    const float qx = cb[v * 3 + 0];
    const float qy = cb[v * 3 + 1];
    const float qz = cb[v * 3 + 2];
    const float sqq = f_sq3(qx, qy, qz);

    float d2[16];
    #pragma unroll
    for (int i = 0; i < 16; i++) {
        int j = tid + i * 256;
        float xj = cb[j * 3 + 0], yj = cb[j * 3 + 1], zj = cb[j * 3 + 2];
        float sqj = f_sq3(xj, yj, zj);
        float dt  = f_dot3(qx, qy, qz, xj, yj, zj);
        d2[i] = __fsub_rn(__fadd_rn(sqq, sqj), __fmul_rn(2.0f, dt));
    }

    unsigned used = 0;
    for (int it = 0; it < 11; it++) {
        float best = 3.4e38f;
        int bi = 0x7fffffff;
        #pragma unroll
        for (int i = 0; i < 16; i++) {
            if (used & (1u << i)) continue;
            if (d2[i] < best) { best = d2[i]; bi = tid + i * 256; }
        }
        sval[tid] = best;
        sidx[tid] = bi;
        __syncthreads();
        for (int s = 128; s > 0; s >>= 1) {
            if (tid < s) {
                float v2 = sval[tid + s];
                int   i2 = sidx[tid + s];
                if (v2 < sval[tid] || (v2 == sval[tid] && i2 < sidx[tid])) {
                    sval[tid] = v2; sidx[tid] = i2;
                }
            }
            __syncthreads();
        }
        int w = sidx[0] & 4095;
        __syncthreads();
        if (it >= 1 && tid == 0) sKnn[it - 1] = w;
        if ((w & 255) == tid) used |= 1u << (w >> 8);
    }
    __syncthreads();

    sTokA[tid] = tok[(size_t)q * DDIM + tid];
    for (int nb = 0; nb < KNN_K; nb++)
        sTokN[nb][tid] = tok[(size_t)(base + sKnn[nb]) * DDIM + tid];
    __syncthreads();

    if (tid < 64) {
        float a = 0.0f;
        for (int k = 0; k < 256; k++)
            a = __fmaf_rn(sTokA[k], W1[k * 64 + tid], a);
        sAH[tid] = a;
    }
    __syncthreads();

    for (int idx = tid; idx < KNN_K * 64; idx += 256) {
        int nb = idx >> 6;
        int h  = idx & 63;
        float acc = sAH[h];
        const float* tn = sTokN[nb];
        for (int k = 0; k < 256; k++)
            acc = __fmaf_rn(tn[k], W1[(256 + k) * 64 + h], acc);
        #pragma unroll
        for (int c = 0; c < 3; c++) {
            float rel = __fsub_rn(cb[sKnn[nb] * 3 + c], cb[v * 3 + c]);
            acc = __fmaf_rn(rel, W1[(512 + c) * 64 + h], acc);
        }
        float hid = __fadd_rn(acc, b1[h]);
        sHid[nb][h] = hid > 0.0f ? hid : 0.0f;
    }
    __syncthreads();

    if (tid < KNN_K) {
        float s = 0.0f;
        for (int h = 0; h < 64; h++)
            s = __fmaf_rn(sHid[tid][h], W2[h], s);
        sSc[tid] = s;
    }
    __syncthreads();

    if (tid == 0) {
        unsigned um = 0;
        #pragma unroll
        for (int s = 0; s < TK; s++) {
            float best = -3.4e38f; int bj = 0;
            for (int jj = 0; jj < KNN_K; jj++) {
                if (um & (1u << jj)) continue;
                if (sSc[jj] > best) { best = sSc[jj]; bj = jj; }
            }
            um |= 1u << bj;
            sSel[s] = bj;
        }
    }
    __syncthreads();

    int ss[TK];
    float k_acc[TK], v_acc[TK];
    #pragma unroll
    for (int s = 0; s < TK; s++) {
        ss[s] = sSel[s];
        k_acc[s] = bk[tid];
        v_acc[s] = bv[tid];
    }
    float q_acc = bq[tid];

    for (int k = 0; k < 256; k++) {
        float wq = Wq[k * 256 + tid];
        float wk = Wk[k * 256 + tid];
        float wv = Wv[k * 256 + tid];
        q_acc += sTokA[k] * wq;
        #pragma unroll
        for (int s = 0; s < TK; s++) {
            float x = sTokN[ss[s]][k];
            k_acc[s] += x * wk;
            v_acc[s] += x * wv;
        }
    }

    #pragma unroll
    for (int s = 0; s < TK; s++) sP[s][tid] = q_acc * k_acc[s];
    __syncthreads();

    if (tid < 16) {
        int h = tid >> 2, s = tid & 3;
        float p = 0.0f;
        for (int d = 0; d < 64; d++) p += sP[s][h * 64 + d];
        sAtt[h][s] = p * 0.125f;
    }
    __syncthreads();

    const int hh = tid >> 6;
    float a0 = sAtt[hh][0], a1 = sAtt[hh][1], a2 = sAtt[hh][2], a3 = sAtt[hh][3];
    float mx  = fmaxf(fmaxf(a0, a1), fmaxf(a2, a3));
    float e0 = expf(a0 - mx), e1 = expf(a1 - mx), e2 = expf(a2 - mx), e3 = expf(a3 - mx);
    float inv = 1.0f / (e0 + e1 + e2 + e3);
    float o = (e0 * v_acc[0] + e1 * v_acc[1] + e2 * v_acc[2] + e3 * v_acc[3]) * inv;

    sO[tid] = o;
    __syncthreads();

    float a = bo[tid];
    for (int e = 0; e < 256; e++) a += sO[e] * Wo[e * 256 + tid];
    int oidx = q * DDIM + tid;
    if (oidx < out_size)
        out[oidx] = a;
}

// ---------------------------------------------------------------------------
// Launcher. ABI-bilingual size-walk (validated r8-r11). r24 ws layout:
//   sel       @ 0          : 16384*4*4   =    262,144
//   AN        @ 262,144    : 16384*128*4 =  8,388,608  (ends  8,650,752)
//   attnout   @ 262,144    : 16384*256*4 = 16,777,216  (ends 17,039,360) ALIAS of AN
//   qkv       @ 17,039,360 : 16384*768*4 = 50,331,648  (ends 67,371,008)
//   cxyzs     @ 67,371,008 : 16384*16    =    262,144  (ends 67,633,152)
//   cellOff   @ 67,633,152 : 4*4097*4    =     65,552  (ends 67,698,704)
//   sortedIdx @ 67,698,704 : 4*4096*4    =     65,536  (ends 67,764,240)
// NEED = 67,764,240 < 75,497,472 (r11-confirmed available).
// Order: grid_build -> qkv_an -> knn -> attn -> wo. Stream order safe.
// ---------------------------------------------------------------------------
extern "C" void kernel_launch(void* const* d_in, const int* in_sizes, int n_in,
                              void* d_out, int out_size, void* d_ws, size_t ws_size,
                              hipStream_t stream)
{
    const long long want[13] = {4194304LL, 49152LL, 32960LL, 64LL, 64LL,
                                65536LL, 256LL, 65536LL, 256LL,
                                65536LL, 256LL, 65536LL, 256LL};
    int idx[13];
    const int n = n_in;

    const long long* s64 = (const long long*)(const void*)in_sizes;
    const int*       s32 = in_sizes;

    bool ok = false;

    if (n >= 13 && s64[0] == want[0]) {   // int64 interpretation (gated)
        ok = true;
        int walk = 0;
        for (int t = 0; t < 13; t++) {
            int f = -1;
            for (int i = walk; i < n; i++) {
                if (s64[i] == want[t]) { f = i; break; }
            }
            if (f < 0) { ok = false; break; }
            idx[t] = f; walk = f + 1;
        }
    }

    if (!ok) {                            // int32 interpretation
        ok = true;
        int walk = 0;
        for (int t = 0; t < 13; t++) {
            int f = -1;
            for (int i = walk; i < n; i++) {
                if ((long long)s32[i] == want[t]) { f = i; break; }
            }
            if (f < 0) { ok = false; break; }
            idx[t] = f; walk = f + 1;
        }
    }

    if (!ok) return;   // unexpected layout: clean failure, no crash

    const float* tok    = (const float*)d_in[idx[0]];
    const float* coords = (const float*)d_in[idx[1]];
    const float* W1     = (const float*)d_in[idx[2]];
    const float* b1     = (const float*)d_in[idx[3]];
    const float* W2     = (const float*)d_in[idx[4]];
    const float* Wq     = (const float*)d_in[idx[5]];
    const float* bq     = (const float*)d_in[idx[6]];
    const float* Wk     = (const float*)d_in[idx[7]];
    const float* bk     = (const float*)d_in[idx[8]];
    const float* Wv     = (const float*)d_in[idx[9]];
    const float* bv     = (const float*)d_in[idx[10]];
    const float* Wo     = (const float*)d_in[idx[11]];
    const float* bo     = (const float*)d_in[idx[12]];
    float* out = (float*)d_out;

    const size_t NEED = 67764240;
    if (ws_size >= NEED) {
        char* ws = (char*)d_ws;
        int*    sel     = (int*)   (ws + 0);
        float*  AN      = (float*) (ws + 262144);
        float*  attnout = (float*) (ws + 262144);    // aliases AN (dead after K1)
        float*  qkv     = (float*) (ws + 17039360);
        float4* cxyzs   = (float4*)(ws + 67371008);
        int*    cellOff = (int*)   (ws + 67633152);
        int*    sortIdx = (int*)   (ws + 67698704);

        grid_build_kernel<<<dim3(4), dim3(256), 0, stream>>>(coords, cellOff, sortIdx);
        qkv_an_gemm_kernel<<<dim3(128, 14), dim3(256), 0, stream>>>(
            tok, Wq, bq, Wk, bk, Wv, bv, W1, coords, qkv, AN, cxyzs);
        knn_score_kernel<<<dim3(4096), dim3(256), 0, stream>>>(
            AN, cxyzs, cellOff, sortIdx, W1, b1, W2, sel);
        attn_gather_kernel<<<dim3(16384), dim3(256), 0, stream>>>(qkv, sel, attnout);
        wo_gemm_kernel<<<dim3(128, 4), dim3(256), 0, stream>>>(attnout, Wo, bo, out);
    } else {
        fused_voxel_attn<<<dim3(16384), dim3(256), 0, stream>>>(
            tok, coords, W1, b1, W2, Wq, bq, Wk, bk, Wv, bv, Wo, bo, out, out_size);
    }
}